// Round 14
// baseline (203.029 us; speedup 1.0000x reference)
//
#include <hip/hip_runtime.h>
#include <hip/hip_bf16.h>
#include <cstdint>
#include <cstddef>

// ---------------------------------------------------------------------------
// MHA: x[4,2048,1024] -> out[4,2048,1024], fp32 I/O, bf16 MFMA internals.
// ---------------------------------------------------------------------------

typedef __attribute__((ext_vector_type(8))) __bf16 bf16v8;
typedef __attribute__((ext_vector_type(4))) float f32x4;
typedef __attribute__((ext_vector_type(16))) float f32x16;
typedef __attribute__((ext_vector_type(8))) unsigned short u16x8;
typedef __attribute__((ext_vector_type(4))) unsigned u32x4;
typedef unsigned short ushort_t;

#define AS3(p) ((__attribute__((address_space(3))) void*)(p))
#define AS1C(p) ((const __attribute__((address_space(1))) void*)(p))

__device__ __forceinline__ ushort_t f2bf(float f) {
  unsigned u = __builtin_bit_cast(unsigned, f);
  unsigned r = u + 0x7FFFu + ((u >> 16) & 1u);   // RNE
  return (ushort_t)(r >> 16);
}

__device__ __forceinline__ unsigned cvt_pk_bf16(float lo, float hi) {
  unsigned r;
  asm("v_cvt_pk_bf16_f32 %0, %1, %2" : "=v"(r) : "v"(lo), "v"(hi));
  return r;
}

// v_permlane32_swap_b32 vdst, vsrc : vdst.hi <-> vsrc.lo (lane i+32 <-> lane i)
__device__ __forceinline__ void plswap(unsigned& x, unsigned& y) {
  asm("v_permlane32_swap_b32 %0, %1" : "+v"(x), "+v"(y));
}

// raw v_exp_f32 (2^x). Scores are bounded (|log2-score| < ~40): no overflow;
// subnormal flush-to-zero is the correct limit for vanished softmax terms.
__device__ __forceinline__ float exp2_raw(float x) {
  float r;
  asm("v_exp_f32 %0, %1" : "=v"(r) : "v"(x));
  return r;
}

constexpr int B_ = 4, S_ = 2048, D_ = 1024, H_ = 16, DK_ = 64;
constexpr int M_ = B_ * S_;          // 8192 rows (b,s)
constexpr int NQKV_ = 3 * H_ * DK_;  // 3072
// fold 1/sqrt(dk) * log2(e) into W_Q so scores are in log2-space
constexpr float QSCALE = 0.125f * 1.44269504088896f;

// ---------------------------------------------------------------------------
// x fp32 -> bf16, 8 elems/thread.  Output PRE-SWIZZLED for the GEMMs:
// 16B chunk index i goes to i ^ ((i>>8)&3)  (== col-chunk ^ (row>>1)&3).
__global__ __launch_bounds__(256) void cast_x_kernel(const float* __restrict__ x,
                                                     ushort_t* __restrict__ xb) {
  size_t i = (size_t)blockIdx.x * 256 + threadIdx.x;  // 16B-chunk index
  const float4* px = (const float4*)(x + i * 8);
  float4 a = px[0], b = px[1];
  u16x8 v;
  v[0] = f2bf(a.x); v[1] = f2bf(a.y); v[2] = f2bf(a.z); v[3] = f2bf(a.w);
  v[4] = f2bf(b.x); v[5] = f2bf(b.y); v[6] = f2bf(b.z); v[7] = f2bf(b.w);
  size_t di = i ^ ((i >> 8) & 3);
  *(u16x8*)(xb + di * 8) = v;
}

// ---------------------------------------------------------------------------
// W_Q/W_K/W_V [H][D][dk] f32 -> wqkv_t [p][h][dk][D] bf16 (B^T layout,
// pre-swizzled: elem idx -> idx ^ (((idx>>11)&3)<<3), == chunk ^ (dk>>1)&3).
// LDS-tiled transpose with coalesced reads/writes.
__global__ __launch_bounds__(256) void prep_wqkv_kernel(const float* __restrict__ Wq,
                                                        const float* __restrict__ Wk,
                                                        const float* __restrict__ Wv,
                                                        ushort_t* __restrict__ dst) {
  __shared__ ushort_t lt[64 * 264];
  const int t = threadIdx.x;
  const int blk = blockIdx.x;            // 192 = p(3) x h(16) x dchunk(4)
  const int p = blk >> 6;
  const int rem = blk & 63;
  const int h = rem >> 2, d0 = (rem & 3) << 8;
  const float* W = (p == 0) ? Wq : ((p == 1) ? Wk : Wv);
  const float sc = (p == 0) ? QSCALE : 1.0f;
  const int rt = t >> 4, cq = (t & 15) << 2;
#pragma unroll
  for (int it = 0; it < 16; ++it) {
    int r = it * 16 + rt;                // d-offset 0..255
    float4 v = *(const float4*)(W + (h << 16) + (size_t)(d0 + r) * 64 + cq);
    lt[(cq + 0) * 264 + r] = f2bf(v.x * sc);
    lt[(cq + 1) * 264 + r] = f2bf(v.y * sc);
    lt[(cq + 2) * 264 + r] = f2bf(v.z * sc);
    lt[(cq + 3) * 264 + r] = f2bf(v.w * sc);
  }
  __syncthreads();
  const int c8 = t & 31;                 // 16B chunk within the 256-d segment
#pragma unroll
  for (int it = 0; it < 8; ++it) {
    int dk = it * 8 + (t >> 5);
    u16x8 v = *(const u16x8*)&lt[dk * 264 + c8 * 8];
    int s = (dk >> 1) & 3;
    *(u16x8*)(dst + ((p << 20) | (h << 16) | (dk << 10)) + d0 + ((c8 ^ s) << 3)) = v;
  }
}

// W_O [K=1024][N=1024] f32 -> wo_t [N][K] bf16 (pre-swizzled, chunk ^ (n>>1)&3).
__global__ __launch_bounds__(256) void prep_wo_kernel(const float* __restrict__ Wo,
                                                      ushort_t* __restrict__ dst) {
  __shared__ ushort_t lt[64 * 264];
  const int t = threadIdx.x;
  const int n0 = (blockIdx.x >> 2) << 6;   // 16 n-tiles of 64
  const int k0 = (blockIdx.x & 3) << 8;    // 4 k-tiles of 256
  const int rt = t >> 4, nq = (t & 15) << 2;
#pragma unroll
  for (int it = 0; it < 16; ++it) {
    int kr = it * 16 + rt;                 // k-offset 0..255
    float4 v = *(const float4*)(Wo + (size_t)(k0 + kr) * 1024 + n0 + nq);
    lt[(nq + 0) * 264 + kr] = f2bf(v.x);
    lt[(nq + 1) * 264 + kr] = f2bf(v.y);
    lt[(nq + 2) * 264 + kr] = f2bf(v.z);
    lt[(nq + 3) * 264 + kr] = f2bf(v.w);
  }
  __syncthreads();
  const int c8 = t & 31;
#pragma unroll
  for (int it = 0; it < 8; ++it) {
    int nr = it * 8 + (t >> 5);
    u16x8 v = *(const u16x8*)&lt[nr * 264 + c8 * 8];
    int n = n0 + nr;
    int s = (n >> 1) & 3;
    *(u16x8*)(dst + (size_t)n * 1024 + k0 + ((c8 ^ s) << 3)) = v;
  }
}

// ---------------------------------------------------------------------------
// QKV GEMM v2: 256x128 tile, BK=32, 8 waves (2Mx4N -> 128x32/wave), 4-deep
// 24KB ring (96KB LDS), counted vmcnt (3 loads/wave/tile, steady VMW(6)),
// raw s_barrier per tile, T2 swizzle via pre-swizzled sources (#21).
// Grid = 32x24 = 768 = exactly 3 blocks/CU -> three even passes (no
// pass-quantization tail of the former 384-block/256^2 version).
// Epilogue: 64KB C-tile staged in the dead ring LDS (V third transposed),
// then 16B coalesced scatter to Q / K-tiles / V-tiles (16-slot XOR).
#define VMW(N) asm volatile("s_waitcnt vmcnt(" N ")" ::: "memory")
#define BAR() asm volatile("s_barrier" ::: "memory")

#define QSTAGE(T)                                                                   \
  {                                                                                 \
    const int pb = ((T) & 3) * 24576;                                               \
    __builtin_amdgcn_global_load_lds(AS1C(gA0), AS3(lds + pb + wid * 2048), 16, 0, 0); \
    __builtin_amdgcn_global_load_lds(AS1C(gA1), AS3(lds + pb + wid * 2048 + 1024), 16, 0, 0); \
    __builtin_amdgcn_global_load_lds(AS1C(gB0), AS3(lds + pb + 16384 + wid * 1024), 16, 0, 0); \
    gA0 += 32; gA1 += 32; gB0 += 32;                                                \
  }

#define QBODY(T, VMSTR, DO_STAGE)                                                   \
  {                                                                                 \
    const int cb = ((T) & 3) * 24576;                                               \
    VMW(VMSTR);                                                                     \
    BAR();                                                                          \
    if (DO_STAGE) QSTAGE((T) + 3);                                                  \
    bf16v8 af[8], bfr[2];                                                           \
    _Pragma("unroll")                                                               \
    for (int i = 0; i < 8; ++i)                                                     \
      af[i] = *(const bf16v8*)(lds + cb + awo + i * 1024);                          \
    _Pragma("unroll")                                                               \
    for (int j = 0; j < 2; ++j)                                                     \
      bfr[j] = *(const bf16v8*)(lds + cb + bwo + j * 1024);                         \
    __builtin_amdgcn_s_setprio(1);                                                  \
    _Pragma("unroll")                                                               \
    for (int i = 0; i < 8; ++i)                                                     \
      _Pragma("unroll")                                                             \
      for (int j = 0; j < 2; ++j)                                                   \
        acc[i][j] = __builtin_amdgcn_mfma_f32_16x16x32_bf16(af[i], bfr[j], acc[i][j], 0, 0, 0); \
    __builtin_amdgcn_s_setprio(0);                                                  \
  }

__global__ __launch_bounds__(512) void gemm256_qkv(
    const ushort_t* __restrict__ A, const ushort_t* __restrict__ Bt,
    ushort_t* __restrict__ qb, ushort_t* __restrict__ kb, ushort_t* __restrict__ vt) {
  extern __shared__ __align__(16) char lds[];  // 98304 = 4 bufs x (A16K + B8K)
  const int tid = threadIdx.x;
  const int wid = tid >> 6, lane = tid & 63;
  const int g = lane >> 4, lq = lane & 15;
  const int wm = wid >> 2, wn = wid & 3;
  // XCD-aware bijective swizzle (768 % 8 == 0): 96 consecutive wgs per XCD
  const int bid = blockIdx.x;
  const int wg = (bid & 7) * 96 + (bid >> 3);
  const int mb = wg / 24, nb = wg % 24;
  const int m0 = mb * 256, n0 = nb * 128;

  // swizzled per-lane ds_read col offset: chunk' = g ^ ((row>>1)&3), row&15==lq
  const int co = (g ^ ((lq >> 1) & 3)) * 16;
  const int awo = wm * 8192 + lq * 64 + co;            // A frag base (+i*1024)
  const int bwo = 16384 + wn * 2048 + lq * 64 + co;    // B frag base (+j*1024)

  // stage source pointers (linear copy; sources are pre-swizzled).
  // A: wave wid covers rows wid*32..+31 (2 loads); B: rows wid*16..+15.
  const ushort_t* gA0 = A + (size_t)(m0 + wid * 32 + (lane >> 2)) * 1024 + (lane & 3) * 8;
  const ushort_t* gA1 = gA0 + (size_t)16 * 1024;
  const ushort_t* gB0 = Bt + (size_t)(n0 + wid * 16 + (lane >> 2)) * 1024 + (lane & 3) * 8;

  f32x4 acc[8][2] = {};

  // prologue: stage K-tiles 0,1,2 (9 loads/wave in flight)
  QSTAGE(0); QSTAGE(1); QSTAGE(2);

  for (int t = 0; t < 29; ++t) QBODY(t, "6", true);   // t=28 stages tile 31
  QBODY(29, "6", false);
  QBODY(30, "3", false);
  QBODY(31, "0", false);

  // ---- epilogue: acc -> LDS bf16 C-tile (256x128; V third transposed) ----
  asm volatile("s_waitcnt lgkmcnt(0)" ::: "memory");
  BAR();
  const int p = n0 >> 10;  // uniform per block (128 | 1024)
  if (p == 2) {
    // transposed: element (row s, col v) at byte (col*512 + row*2) ^ ((col&7)<<4)
#pragma unroll
    for (int i = 0; i < 8; ++i)
#pragma unroll
      for (int j = 0; j < 2; ++j) {
        int col = wn * 32 + j * 16 + lq;          // 0..127
        int swz = (col & 7) << 4;
#pragma unroll
        for (int r = 0; r < 4; ++r) {
          int row = wm * 128 + i * 16 + g * 4 + r;  // 0..255
          *(ushort_t*)(lds + ((col * 512 + row * 2) ^ swz)) = f2bf(acc[i][j][r]);
        }
      }
  } else {
    // row-major: element (row,col) at byte (row*256 + col*2) ^ ((row&7)<<4)
#pragma unroll
    for (int i = 0; i < 8; ++i)
#pragma unroll
      for (int j = 0; j < 2; ++j) {
        int col = wn * 32 + j * 16 + lq;
#pragma unroll
        for (int r = 0; r < 4; ++r) {
          int row = wm * 128 + i * 16 + g * 4 + r;
          *(ushort_t*)(lds + ((row * 256 + col * 2) ^ ((row & 7) << 4))) = f2bf(acc[i][j][r]);
        }
      }
  }
  asm volatile("s_waitcnt lgkmcnt(0)" ::: "memory");
  BAR();

  // ---- coalesced 16B stores: 4096 chunks = 8/thread ----
  if (p == 0) {
#pragma unroll
    for (int it = 0; it < 8; ++it) {
      int ci = it * 512 + tid;
      int row = ci >> 4, ch = ci & 15;            // 16 chunks per 256B row
      u16x8 v = *(const u16x8*)(lds + ((row * 256 + ch * 16) ^ ((row & 7) << 4)));
      int gcol = n0 + ch * 8;
      int h = (gcol >> 6) & 15, dd0 = gcol & 63;
      int grow = m0 + row;
      int b = grow >> 11, s = grow & 2047;
      size_t bh = (size_t)(b * 16 + h);
      *(u16x8*)(qb + (bh * 2048 + s) * 64 + dd0) = v;
    }
  } else if (p == 1) {
#pragma unroll
    for (int it = 0; it < 8; ++it) {
      int ci = it * 512 + tid;
      int row = ci >> 4, ch = ci & 15;
      u16x8 v = *(const u16x8*)(lds + ((row * 256 + ch * 16) ^ ((row & 7) << 4)));
      int gcol = n0 + ch * 8;
      int h = (gcol >> 6) & 15, dd0 = gcol & 63;
      int grow = m0 + row;
      int b = grow >> 11, s = grow & 2047;
      size_t bh = (size_t)(b * 16 + h);
      int tt = s >> 6, sIn = s & 63;
      int byte = (sIn * 128 + dd0 * 2) ^ ((sIn & 15) << 4);   // 16-slot XOR
      *(u16x8*)((char*)kb + (((size_t)bh * 32 + tt) << 13) + byte) = v;
    }
  } else {
#pragma unroll
    for (int it = 0; it < 8; ++it) {
      int ci = it * 512 + tid;
      int crow = ci >> 5, ch = ci & 31;   // crow = v-col 0..127; ch*8 = s-chunk
      u16x8 v = *(const u16x8*)(lds + ((crow * 512 + ch * 16) ^ ((crow & 7) << 4)));
      int gcol = n0 + crow;
      int h = (gcol >> 6) & 15, dd = gcol & 63;
      int grow = m0 + ch * 8;
      int b = grow >> 11, s = grow & 2047;
      size_t bh = (size_t)(b * 16 + h);
      int tt = s >> 6, sIn0 = s & 63;
      int byte = (dd * 128 + sIn0 * 2) ^ ((dd & 15) << 4);    // 16-slot XOR
      *(u16x8*)((char*)vt + (((size_t)bh * 32 + tt) << 13) + byte) = v;
    }
  }
}

// ---------------------------------------------------------------------------
// Out-projection GEMM: C[8192][1024] fp32 = a_out x wo_t^T.
// 128x128 tile, BK=32, 4 waves, 4-deep 16KB ring (64KB LDS -> 2 blocks/CU),
// counted vmcnt, T2 swizzle via pre-swizzled sources.  Grid 512, XCD-swz.
#define PSTAGE(T)                                                                   \
  {                                                                                 \
    const int pb = ((T) & 3) * 16384;                                               \
    __builtin_amdgcn_global_load_lds(AS1C(gA0), AS3(lds + pb + wid * 1024), 16, 0, 0); \
    __builtin_amdgcn_global_load_lds(AS1C(gA1), AS3(lds + pb + 4096 + wid * 1024), 16, 0, 0); \
    __builtin_amdgcn_global_load_lds(AS1C(gB0), AS3(lds + pb + 8192 + wid * 1024), 16, 0, 0); \
    __builtin_amdgcn_global_load_lds(AS1C(gB1), AS3(lds + pb + 12288 + wid * 1024), 16, 0, 0); \
    gA0 += 32; gA1 += 32; gB0 += 32; gB1 += 32;                                     \
  }

#define PBODY(T, VMSTR, DO_STAGE)                                                   \
  {                                                                                 \
    const int cb = ((T) & 3) * 16384;                                               \
    VMW(VMSTR);                                                                     \
    BAR();                                                                          \
    if (DO_STAGE) PSTAGE((T) + 3);                                                  \
    bf16v8 af[4], bfr[4];                                                           \
    _Pragma("unroll")                                                               \
    for (int i = 0; i < 4; ++i)                                                     \
      af[i] = *(const bf16v8*)(lds + cb + awo + i * 1024);                          \
    _Pragma("unroll")                                                               \
    for (int j = 0; j < 4; ++j)                                                     \
      bfr[j] = *(const bf16v8*)(lds + cb + bwo + j * 1024);                         \
    __builtin_amdgcn_s_setprio(1);                                                  \
    _Pragma("unroll")                                                               \
    for (int i = 0; i < 4; ++i)                                                     \
      _Pragma("unroll")                                                             \
      for (int j = 0; j < 4; ++j)                                                   \
        acc[i][j] = __builtin_amdgcn_mfma_f32_16x16x32_bf16(af[i], bfr[j], acc[i][j], 0, 0, 0); \
    __builtin_amdgcn_s_setprio(0);                                                  \
  }

__global__ __launch_bounds__(256) void gemm128_op(
    const ushort_t* __restrict__ A, const ushort_t* __restrict__ Bt,
    float* __restrict__ Cf) {
  extern __shared__ __align__(16) char lds[];  // 65536 = 4 bufs x (A8K + B8K)
  const int tid = threadIdx.x;
  const int wid = tid >> 6, lane = tid & 63;
  const int g = lane >> 4, lq = lane & 15;
  const int wm = wid >> 1, wn = wid & 1;
  // XCD-aware bijective swizzle (512 % 8 == 0): 64 consecutive wgs per XCD
  const int bid = blockIdx.x;
  const int wg = (bid & 7) * 64 + (bid >> 3);
  const int mb = wg >> 3, nb = wg & 7;
  const int m0 = mb * 128, n0 = nb * 128;

  // swizzled per-lane ds_read col offset: chunk' = g ^ ((row>>1)&3), row&15==lq
  const int co = (g ^ ((lq >> 1) & 3)) * 16;
  const int awo = wm * 4096 + lq * 64 + co;           // A frag base (+i*1024)
  const int bwo = 8192 + wn * 4096 + lq * 64 + co;    // B frag base (+j*1024)

  // stage source pointers (linear copy; sources are pre-swizzled)
  const ushort_t* gA0 = A + (size_t)(m0 + (tid >> 2)) * 1024 + (tid & 3) * 8;
  const ushort_t* gA1 = gA0 + (size_t)64 * 1024;
  const ushort_t* gB0 = Bt + (size_t)(n0 + (tid >> 2)) * 1024 + (tid & 3) * 8;
  const ushort_t* gB1 = gB0 + (size_t)64 * 1024;

  f32x4 acc[4][4] = {};

  // prologue: stage K-tiles 0,1,2 (12 loads/wave in flight)
  PSTAGE(0); PSTAGE(1); PSTAGE(2);

  for (int t = 0; t < 29; ++t) PBODY(t, "8", true);   // t=28 stages tile 31
  PBODY(29, "8", false);
  PBODY(30, "4", false);
  PBODY(31, "0", false);

  // epilogue: direct fp32 stores (16-lane 64B runs)
#pragma unroll
  for (int i = 0; i < 4; ++i)
#pragma unroll
    for (int j = 0; j < 4; ++j)
#pragma unroll
      for (int r = 0; r < 4; ++r) {
        int row = m0 + wm * 64 + i * 16 + g * 4 + r;
        int col = n0 + wn * 64 + j * 16 + lq;
        Cf[(size_t)row * 1024 + col] = acc[i][j][r];
      }
}

// ---------------------------------------------------------------------------
// Flash attention v9: 32x32 swapped-QK^T, in-register P, NO-MAX softmax,
// KVBLK=64, 2-buf 32KB static LDS, grid 1024, counted-vmcnt double-barrier.
// K/V tiles use the 16-slot XOR ((row&15)<<4): 2-way LDS alias = free.
__device__ __forceinline__ void softpack(const f32x16& s0, const f32x16& s1,
                                         float& lsum, bf16v8& pa0, bf16v8& pa1,
                                         bf16v8& pa2, bf16v8& pa3) {
  float e0[16], e1[16];
#pragma unroll
  for (int r = 0; r < 16; ++r) e0[r] = exp2_raw(s0[r]);
#pragma unroll
  for (int r = 0; r < 16; ++r) e1[r] = exp2_raw(s1[r]);
  float ad[16];
#pragma unroll
  for (int r = 0; r < 16; ++r) ad[r] = e0[r] + e1[r];
#pragma unroll
  for (int st = 8; st >= 1; st >>= 1)
#pragma unroll
    for (int r = 0; r < st; ++r) ad[r] += ad[r + st];
  lsum += ad[0];
  unsigned a0 = cvt_pk_bf16(e0[0], e0[1]), b0 = cvt_pk_bf16(e0[4], e0[5]);
  unsigned a1 = cvt_pk_bf16(e0[2], e0[3]), b1 = cvt_pk_bf16(e0[6], e0[7]);
  unsigned a2 = cvt_pk_bf16(e0[8], e0[9]), b2 = cvt_pk_bf16(e0[12], e0[13]);
  unsigned a3 = cvt_pk_bf16(e0[10], e0[11]), b3 = cvt_pk_bf16(e0[14], e0[15]);
  unsigned a4 = cvt_pk_bf16(e1[0], e1[1]), b4 = cvt_pk_bf16(e1[4], e1[5]);
  unsigned a5 = cvt_pk_bf16(e1[2], e1[3]), b5 = cvt_pk_bf16(e1[6], e1[7]);
  unsigned a6 = cvt_pk_bf16(e1[8], e1[9]), b6 = cvt_pk_bf16(e1[12], e1[13]);
  unsigned a7 = cvt_pk_bf16(e1[10], e1[11]), b7 = cvt_pk_bf16(e1[14], e1[15]);
  plswap(a0, b0); plswap(a1, b1); plswap(a2, b2); plswap(a3, b3);
  plswap(a4, b4); plswap(a5, b5); plswap(a6, b6); plswap(a7, b7);
  pa0 = __builtin_bit_cast(bf16v8, u32x4{a0, a1, b0, b1});  // kv  0..15
  pa1 = __builtin_bit_cast(bf16v8, u32x4{a2, a3, b2, b3});  // kv 16..31
  pa2 = __builtin_bit_cast(bf16v8, u32x4{a4, a5, b4, b5});  // kv 32..47
  pa3 = __builtin_bit_cast(bf16v8, u32x4{a6, a7, b6, b7});  // kv 48..63
}

#define MFMA32(a, b, c) __builtin_amdgcn_mfma_f32_32x32x16_bf16(a, b, c, 0, 0, 0)

#define ASTAGE(T)                                                                   \
  {                                                                                 \
    const int pb = ((T) & 1) * 16384;                                               \
    const char* ks = kbase + ((size_t)(T) << 13);                                   \
    const char* vs = vbase + ((size_t)(T) << 13);                                   \
    _Pragma("unroll")                                                               \
    for (int j = 0; j < 2; ++j) {                                                   \
      __builtin_amdgcn_global_load_lds(AS1C(ks + w * 2048 + j * 1024 + lane * 16),  \
                                       AS3(smem + pb + w * 2048 + j * 1024), 16, 0, 0); \
      __builtin_amdgcn_global_load_lds(AS1C(vs + w * 2048 + j * 1024 + lane * 16),  \
                                       AS3(smem + pb + 8192 + w * 2048 + j * 1024), 16, 0, 0); \
    }                                                                               \
  }

#define ACOMPUTE(T)                                                                 \
  {                                                                                 \
    const char* bk = smem + ((T) & 1) * 16384;                                      \
    bf16v8 kf0[4], kf1[4], vfr[2][4];                                               \
    _Pragma("unroll")                                                               \
    for (int c = 0; c < 4; ++c) {                                                   \
      kf0[c] = *(const bf16v8*)(bk + addr4[c]);                                     \
      kf1[c] = *(const bf16v8*)(bk + addr4[c] + 4096);                              \
    }                                                                               \
    _Pragma("unroll")                                                               \
    for (int nb = 0; nb < 2; ++nb)                                                  \
      _Pragma("unroll")                                                             \
      for (int ks2 = 0; ks2 < 4; ++ks2)                                             \
        vfr[nb][ks2] = *(const bf16v8*)(bk + addr4[ks2] + 8192 + nb * 4096);        \
    f32x16 s0 = {}, s1 = {};                                                        \
    __builtin_amdgcn_s_setprio(1);                                                  \
    _Pragma("unroll")                                                               \
    for (int c = 0; c < 4; ++c) {                                                   \
      s0 = MFMA32(kf0[c], qf[c], s0);                                               \
      s1 = MFMA32(kf1[c], qf[c], s1);                                               \
    }                                                                               \
    __builtin_amdgcn_s_setprio(0);                                                  \
    bf16v8 pa0, pa1, pa2, pa3;                                                      \
    softpack(s0, s1, lsum, pa0, pa1, pa2, pa3);                                     \
    __builtin_amdgcn_s_setprio(1);                                                  \
    _Pragma("unroll")                                                               \
    for (int nb = 0; nb < 2; ++nb) {                                                \
      oa[nb] = MFMA32(pa0, vfr[nb][0], oa[nb]);                                     \
      oa[nb] = MFMA32(pa1, vfr[nb][1], oa[nb]);                                     \
      oa[nb] = MFMA32(pa2, vfr[nb][2], oa[nb]);                                     \
      oa[nb] = MFMA32(pa3, vfr[nb][3], oa[nb]);                                     \
    }                                                                               \
    __builtin_amdgcn_s_setprio(0);                                                  \
  }

__global__ __launch_bounds__(256) void attn_kernel(const ushort_t* __restrict__ qb,
                                                   const ushort_t* __restrict__ kt,
                                                   const ushort_t* __restrict__ vt,
                                                   ushort_t* __restrict__ aout) {
  __shared__ __align__(16) char smem[32768];
  __shared__ float cbuf[4][32];
  const int tid = threadIdx.x;
  const int w = tid >> 6, lane = tid & 63;
  const int hi = lane >> 5, l31 = lane & 31;
  // XCD swizzle: the 16 blocks of one bh all share blockIdx%8 -> same XCD L2
  const int bidx = blockIdx.x;           // grid = 1024
  const int xcd = bidx & 7, slot = bidx >> 3;
  const int bh = xcd + 8 * (slot >> 4);  // 0..63
  const int qt = (slot & 15) * 4 + w;    // 0..63 (32-row q tile)
  const char* kbase = (const char*)kt + ((size_t)bh << 18);  // 32 tiles * 8KB
  const char* vbase = (const char*)vt + ((size_t)bh << 18);
  const ushort_t* Qp = qb + (size_t)bh * (S_ * 64) + qt * 32 * 64;

  // Q B-frags: lane holds Q[q=l31][dk = c*16 + hi*8 + e]
  bf16v8 qf[4];
#pragma unroll
  for (int c = 0; c < 4; ++c)
    qf[c] = *(const bf16v8*)(Qp + l31 * 64 + c * 16 + hi * 8);

  // loop-invariant swizzled LDS byte offsets (row = l31, colByte = c*32+hi*16)
  // 16-slot XOR: 32 lanes -> 16 slots = 2-way = free (m136)
  int addr4[4];
#pragma unroll
  for (int c = 0; c < 4; ++c)
    addr4[c] = (l31 * 128 + c * 32 + hi * 16) ^ ((l31 & 15) << 4);

  f32x16 oa[2] = {};            // O[q][dv], dv-blocks of 32
  float lsum = 0.f;             // own-half row sum; cross-half shfl at end

  // prologue: stage tile 0 into buffer 0 (4 loads/wave)
  ASTAGE(0);

#pragma unroll 2
  for (int t = 0; t < 31; ++t) {
    BAR();            // all waves done reading buf[(t+1)&1] (during iter t-1)
    ASTAGE(t + 1);    // 4 loads into buf[(t+1)&1]
    VMW("4");         // own tile-t loads landed; t+1's stay in flight
    BAR();            // all waves' tile-t loads landed
    ACOMPUTE(t);
  }
  BAR();
  VMW("0");           // last tile: drain (nothing left to overlap)
  BAR();
  ACOMPUTE(31);

  // cross-half row-sum (deferred from the loop), then normalize via LDS
  // broadcast-transpose. ob region = buf0 (0..16KB): last compute used buf1.
  lsum += __shfl_xor(lsum, 32);
  ushort_t* ob = (ushort_t*)(smem + w * 4096);
  cbuf[w][l31] = 1.0f / lsum;
  asm volatile("s_waitcnt lgkmcnt(0)" ::: "memory");
#pragma unroll
  for (int rq = 0; rq < 4; ++rq) {
    f32x4 c4 = *(const f32x4*)&cbuf[w][8 * rq + 4 * hi];
#pragma unroll
    for (int j = 0; j < 4; ++j) {
      int row = 8 * rq + 4 * hi + j;
#pragma unroll
      for (int nb = 0; nb < 2; ++nb)
        ob[row * 64 + nb * 32 + l31] = f2bf(oa[nb][4 * rq + j] * c4[j]);
    }
  }
  asm volatile("s_waitcnt lgkmcnt(0)" ::: "memory");
  const int row = lane >> 1, hf = lane & 1;
  const int b = bh >> 4, h = bh & 15;
  const int rowg = b * 2048 + qt * 32 + row;     // global (b,s) row
  const int sx = (rowg >> 1) & 3;                // out-proj pre-swizzle
  size_t rbase = (size_t)rowg * 1024;
#pragma unroll
  for (int i = 0; i < 4; ++i) {
    bf16v8 v = *(const bf16v8*)&ob[row * 64 + hf * 32 + i * 8];
    int c = h * 8 + hf * 4 + i;                  // 16B-chunk index in row
    *(bf16v8*)(aout + rbase + (size_t)((c ^ sx) * 8)) = v;
  }
}

// ---------------------------------------------------------------------------
extern "C" void kernel_launch(void* const* d_in, const int* in_sizes, int n_in,
                              void* d_out, int out_size, void* d_ws, size_t ws_size,
                              hipStream_t stream) {
  const float* x = (const float*)d_in[0];
  const float* Wq = (const float*)d_in[1];
  const float* Wk = (const float*)d_in[2];
  const float* Wv = (const float*)d_in[3];
  const float* Wo = (const float*)d_in[4];
  float* out = (float*)d_out;

  // workspace layout (bytes)
  char* ws = (char*)d_ws;
  constexpr size_t OFF_XB = 0;                       // 16 MB  x bf16 pre-swz
  constexpr size_t OFF_WQKV = 16777216;              // 6 MB   [3][H][dk][D] pre-swz
  constexpr size_t OFF_WO = 23068672;                // 2 MB   [N][K] pre-swz
  constexpr size_t OFF_Q = 25165824;                 // 16 MB  [BH][S][64] raw
  constexpr size_t OFF_K = 41943040;                 // 16 MB  K tiled+attn-swz
  constexpr size_t OFF_V = 58720256;                 // 16 MB  V tiled+attn-swz
  constexpr size_t OFF_AO = 75497472;                // 16 MB  [8192][1024] pre-swz
  constexpr size_t WS_NEEDED = 92274688;
  if (ws_size < WS_NEEDED) return;  // refuse to scribble OOB

  ushort_t* xb = (ushort_t*)(ws + OFF_XB);
  ushort_t* wqkv_t = (ushort_t*)(ws + OFF_WQKV);
  ushort_t* wo_t = (ushort_t*)(ws + OFF_WO);
  ushort_t* q_buf = (ushort_t*)(ws + OFF_Q);
  ushort_t* k_t = (ushort_t*)(ws + OFF_K);
  ushort_t* v_t = (ushort_t*)(ws + OFF_V);
  ushort_t* a_out = (ushort_t*)(ws + OFF_AO);

  cast_x_kernel<<<(M_ * D_ / 8) / 256, 256, 0, stream>>>(x, xb);
  prep_wqkv_kernel<<<192, 256, 0, stream>>>(Wq, Wk, Wv, wqkv_t);
  prep_wo_kernel<<<64, 256, 0, stream>>>(Wo, wo_t);

  gemm256_qkv<<<(M_ / 256) * (NQKV_ / 128), 512, 98304, stream>>>(
      xb, wqkv_t, q_buf, k_t, v_t);

  attn_kernel<<<1024, 256, 0, stream>>>(q_buf, k_t, v_t, a_out);

  gemm128_op<<<(M_ / 128) * (D_ / 128), 256, 65536, stream>>>(a_out, wo_t, out);
}

// Round 15
// 198.439 us; speedup vs baseline: 1.0231x; 1.0231x over previous
//
#include <hip/hip_runtime.h>
#include <hip/hip_bf16.h>
#include <cstdint>
#include <cstddef>

// ---------------------------------------------------------------------------
// MHA: x[4,2048,1024] -> out[4,2048,1024], fp32 I/O, bf16 MFMA internals.
// ---------------------------------------------------------------------------

typedef __attribute__((ext_vector_type(8))) __bf16 bf16v8;
typedef __attribute__((ext_vector_type(4))) float f32x4;
typedef __attribute__((ext_vector_type(16))) float f32x16;
typedef __attribute__((ext_vector_type(8))) unsigned short u16x8;
typedef __attribute__((ext_vector_type(4))) unsigned u32x4;
typedef unsigned short ushort_t;

#define AS3(p) ((__attribute__((address_space(3))) void*)(p))
#define AS1C(p) ((const __attribute__((address_space(1))) void*)(p))

__device__ __forceinline__ ushort_t f2bf(float f) {
  unsigned u = __builtin_bit_cast(unsigned, f);
  unsigned r = u + 0x7FFFu + ((u >> 16) & 1u);   // RNE
  return (ushort_t)(r >> 16);
}

__device__ __forceinline__ unsigned cvt_pk_bf16(float lo, float hi) {
  unsigned r;
  asm("v_cvt_pk_bf16_f32 %0, %1, %2" : "=v"(r) : "v"(lo), "v"(hi));
  return r;
}

// v_permlane32_swap_b32 vdst, vsrc : vdst.hi <-> vsrc.lo (lane i+32 <-> lane i)
__device__ __forceinline__ void plswap(unsigned& x, unsigned& y) {
  asm("v_permlane32_swap_b32 %0, %1" : "+v"(x), "+v"(y));
}

// raw v_exp_f32 (2^x). Scores are bounded (|log2-score| < ~40): no overflow;
// subnormal flush-to-zero is the correct limit for vanished softmax terms.
__device__ __forceinline__ float exp2_raw(float x) {
  float r;
  asm("v_exp_f32 %0, %1" : "=v"(r) : "v"(x));
  return r;
}

constexpr int B_ = 4, S_ = 2048, D_ = 1024, H_ = 16, DK_ = 64;
constexpr int M_ = B_ * S_;          // 8192 rows (b,s)
constexpr int NQKV_ = 3 * H_ * DK_;  // 3072
// fold 1/sqrt(dk) * log2(e) into W_Q so scores are in log2-space
constexpr float QSCALE = 0.125f * 1.44269504088896f;

// ---------------------------------------------------------------------------
// x fp32 -> bf16, 8 elems/thread.  Output PRE-SWIZZLED for the GEMMs:
// 16B chunk index i goes to i ^ ((i>>8)&3)  (== col-chunk ^ (row>>1)&3).
__global__ __launch_bounds__(256) void cast_x_kernel(const float* __restrict__ x,
                                                     ushort_t* __restrict__ xb) {
  size_t i = (size_t)blockIdx.x * 256 + threadIdx.x;  // 16B-chunk index
  const float4* px = (const float4*)(x + i * 8);
  float4 a = px[0], b = px[1];
  u16x8 v;
  v[0] = f2bf(a.x); v[1] = f2bf(a.y); v[2] = f2bf(a.z); v[3] = f2bf(a.w);
  v[4] = f2bf(b.x); v[5] = f2bf(b.y); v[6] = f2bf(b.z); v[7] = f2bf(b.w);
  size_t di = i ^ ((i >> 8) & 3);
  *(u16x8*)(xb + di * 8) = v;
}

// ---------------------------------------------------------------------------
// W_Q/W_K/W_V [H][D][dk] f32 -> wqkv_t [p][h][dk][D] bf16 (B^T layout,
// pre-swizzled: elem idx -> idx ^ (((idx>>11)&3)<<3), == chunk ^ (dk>>1)&3).
// LDS-tiled transpose with coalesced reads/writes.
__global__ __launch_bounds__(256) void prep_wqkv_kernel(const float* __restrict__ Wq,
                                                        const float* __restrict__ Wk,
                                                        const float* __restrict__ Wv,
                                                        ushort_t* __restrict__ dst) {
  __shared__ ushort_t lt[64 * 264];
  const int t = threadIdx.x;
  const int blk = blockIdx.x;            // 192 = p(3) x h(16) x dchunk(4)
  const int p = blk >> 6;
  const int rem = blk & 63;
  const int h = rem >> 2, d0 = (rem & 3) << 8;
  const float* W = (p == 0) ? Wq : ((p == 1) ? Wk : Wv);
  const float sc = (p == 0) ? QSCALE : 1.0f;
  const int rt = t >> 4, cq = (t & 15) << 2;
#pragma unroll
  for (int it = 0; it < 16; ++it) {
    int r = it * 16 + rt;                // d-offset 0..255
    float4 v = *(const float4*)(W + (h << 16) + (size_t)(d0 + r) * 64 + cq);
    lt[(cq + 0) * 264 + r] = f2bf(v.x * sc);
    lt[(cq + 1) * 264 + r] = f2bf(v.y * sc);
    lt[(cq + 2) * 264 + r] = f2bf(v.z * sc);
    lt[(cq + 3) * 264 + r] = f2bf(v.w * sc);
  }
  __syncthreads();
  const int c8 = t & 31;                 // 16B chunk within the 256-d segment
#pragma unroll
  for (int it = 0; it < 8; ++it) {
    int dk = it * 8 + (t >> 5);
    u16x8 v = *(const u16x8*)&lt[dk * 264 + c8 * 8];
    int s = (dk >> 1) & 3;
    *(u16x8*)(dst + ((p << 20) | (h << 16) | (dk << 10)) + d0 + ((c8 ^ s) << 3)) = v;
  }
}

// W_O [K=1024][N=1024] f32 -> wo_t [N][K] bf16 (pre-swizzled, chunk ^ (n>>1)&3).
__global__ __launch_bounds__(256) void prep_wo_kernel(const float* __restrict__ Wo,
                                                      ushort_t* __restrict__ dst) {
  __shared__ ushort_t lt[64 * 264];
  const int t = threadIdx.x;
  const int n0 = (blockIdx.x >> 2) << 6;   // 16 n-tiles of 64
  const int k0 = (blockIdx.x & 3) << 8;    // 4 k-tiles of 256
  const int rt = t >> 4, nq = (t & 15) << 2;
#pragma unroll
  for (int it = 0; it < 16; ++it) {
    int kr = it * 16 + rt;                 // k-offset 0..255
    float4 v = *(const float4*)(Wo + (size_t)(k0 + kr) * 1024 + n0 + nq);
    lt[(nq + 0) * 264 + kr] = f2bf(v.x);
    lt[(nq + 1) * 264 + kr] = f2bf(v.y);
    lt[(nq + 2) * 264 + kr] = f2bf(v.z);
    lt[(nq + 3) * 264 + kr] = f2bf(v.w);
  }
  __syncthreads();
  const int c8 = t & 31;
#pragma unroll
  for (int it = 0; it < 8; ++it) {
    int nr = it * 8 + (t >> 5);
    u16x8 v = *(const u16x8*)&lt[nr * 264 + c8 * 8];
    int n = n0 + nr;
    int s = (n >> 1) & 3;
    *(u16x8*)(dst + (size_t)n * 1024 + k0 + ((c8 ^ s) << 3)) = v;
  }
}

// ---------------------------------------------------------------------------
// 256x256 QKV GEMM v3: BK=32, 8 waves (2Mx4N), **2-deep 32KB ring (64KB LDS
// -> 2 blocks/CU; all 384 blocks co-resident, no sequential pass tail)**,
// attn-verified double-barrier counted vmcnt: BAR; stage(t+1); VMW(4); BAR;
// compute(t).  T2 swizzle via pre-swizzled sources (#21).
// Epilogue: C staged in the 64KB LDS in TWO 128-row phases (V third
// transposed), 16B coalesced scatter (16-slot XOR on K/V tiles).
#define VMW(N) asm volatile("s_waitcnt vmcnt(" N ")" ::: "memory")
#define BAR() asm volatile("s_barrier" ::: "memory")
#define LGKM0() asm volatile("s_waitcnt lgkmcnt(0)" ::: "memory")

#define QSTAGE(T)                                                                   \
  {                                                                                 \
    const int pb = ((T) & 1) * 32768;                                               \
    __builtin_amdgcn_global_load_lds(AS1C(gA0), AS3(lds + pb + wid * 1024), 16, 0, 0); \
    __builtin_amdgcn_global_load_lds(AS1C(gA1), AS3(lds + pb + 8192 + wid * 1024), 16, 0, 0); \
    __builtin_amdgcn_global_load_lds(AS1C(gB0), AS3(lds + pb + 16384 + wid * 1024), 16, 0, 0); \
    __builtin_amdgcn_global_load_lds(AS1C(gB1), AS3(lds + pb + 24576 + wid * 1024), 16, 0, 0); \
    gA0 += 32; gA1 += 32; gB0 += 32; gB1 += 32;                                     \
  }

#define QCOMP(T)                                                                    \
  {                                                                                 \
    const int cb = ((T) & 1) * 32768;                                               \
    bf16v8 af[8], bfr[4];                                                           \
    _Pragma("unroll")                                                               \
    for (int i = 0; i < 8; ++i)                                                     \
      af[i] = *(const bf16v8*)(lds + cb + awo + i * 1024);                          \
    _Pragma("unroll")                                                               \
    for (int j = 0; j < 4; ++j)                                                     \
      bfr[j] = *(const bf16v8*)(lds + cb + bwo + j * 1024);                         \
    __builtin_amdgcn_s_setprio(1);                                                  \
    _Pragma("unroll")                                                               \
    for (int i = 0; i < 8; ++i)                                                     \
      _Pragma("unroll")                                                             \
      for (int j = 0; j < 4; ++j)                                                   \
        acc[i][j] = __builtin_amdgcn_mfma_f32_16x16x32_bf16(af[i], bfr[j], acc[i][j], 0, 0, 0); \
    __builtin_amdgcn_s_setprio(0);                                                  \
  }

__global__ __launch_bounds__(512) void gemm256_qkv(
    const ushort_t* __restrict__ A, const ushort_t* __restrict__ Bt,
    ushort_t* __restrict__ qb, ushort_t* __restrict__ kb, ushort_t* __restrict__ vt) {
  extern __shared__ __align__(16) char lds[];  // 65536 = 2 bufs x (A16K+B16K)
  const int tid = threadIdx.x;
  const int wid = tid >> 6, lane = tid & 63;
  const int g = lane >> 4, lq = lane & 15;
  const int wm = wid >> 2, wn = wid & 3;
  // XCD-aware bijective swizzle (384 % 8 == 0): 48 consecutive wgs per XCD
  const int bid = blockIdx.x;
  const int wg = (bid & 7) * 48 + (bid >> 3);
  const int mb = wg / 12, nb = wg % 12;
  const int m0 = mb * 256, n0 = nb * 256;

  // swizzled per-lane ds_read col offset: chunk' = g ^ ((row>>1)&3), row&15==lq
  const int co = (g ^ ((lq >> 1) & 3)) * 16;
  const int awo = wm * 8192 + lq * 64 + co;            // A frag base (+i*1024)
  const int bwo = 16384 + wn * 4096 + lq * 64 + co;    // B frag base (+j*1024)

  // stage source pointers (linear copy; sources are pre-swizzled)
  const ushort_t* gA0 = A + (size_t)(m0 + (tid >> 2)) * 1024 + (tid & 3) * 8;
  const ushort_t* gA1 = gA0 + (size_t)128 * 1024;
  const ushort_t* gB0 = Bt + (size_t)(n0 + (tid >> 2)) * 1024 + (tid & 3) * 8;
  const ushort_t* gB1 = gB0 + (size_t)128 * 1024;

  f32x4 acc[8][4] = {};

  // prologue: stage tile 0 into buffer 0 (4 loads/wave)
  QSTAGE(0);

  for (int t = 0; t < 31; ++t) {
    BAR();            // all waves done reading buf[(t+1)&1] (during iter t-1)
    QSTAGE(t + 1);    // 4 loads into buf[(t+1)&1]
    VMW("4");         // own tile-t loads landed; t+1's stay in flight
    BAR();            // all waves' tile-t loads landed
    QCOMP(t);
  }
  BAR();
  VMW("0");
  BAR();
  QCOMP(31);

  // ---- epilogue: two 128-row phases through the 64KB LDS ----
  const int p = n0 >> 10;  // uniform per block (256 | 1024)
#pragma unroll
  for (int ph = 0; ph < 2; ++ph) {
    BAR();   // phase-0: LDS ring dead; phase-1: all phase-0 reads consumed
    if (wm == ph) {
      if (p == 2) {
        // transposed: (s-rowrel, col v) at byte (col*256 + rowrel*2) ^ ((col&7)<<4)
#pragma unroll
        for (int i = 0; i < 8; ++i)
#pragma unroll
          for (int j = 0; j < 4; ++j) {
            int col = wn * 64 + j * 16 + lq;
            int swz = (col & 7) << 4;
#pragma unroll
            for (int r = 0; r < 4; ++r) {
              int rowrel = i * 16 + g * 4 + r;   // 0..127 within phase
              *(ushort_t*)(lds + ((col * 256 + rowrel * 2) ^ swz)) = f2bf(acc[i][j][r]);
            }
          }
      } else {
        // row-major: (rowrel, col) at byte (rowrel*512 + col*2) ^ ((rowrel&7)<<4)
#pragma unroll
        for (int i = 0; i < 8; ++i)
#pragma unroll
          for (int j = 0; j < 4; ++j) {
            int col = wn * 64 + j * 16 + lq;
#pragma unroll
            for (int r = 0; r < 4; ++r) {
              int rowrel = i * 16 + g * 4 + r;
              *(ushort_t*)(lds + ((rowrel * 512 + col * 2) ^ ((rowrel & 7) << 4))) = f2bf(acc[i][j][r]);
            }
          }
      }
    }
    LGKM0();
    BAR();
    // ---- coalesced 16B stores: 4096 chunks = 8/thread per phase ----
    if (p == 0) {
#pragma unroll
      for (int it = 0; it < 8; ++it) {
        int ci = it * 512 + tid;
        int rowrel = ci >> 5, ch = ci & 31;
        u16x8 v = *(const u16x8*)(lds + ((rowrel * 512 + ch * 16) ^ ((rowrel & 7) << 4)));
        int gcol = n0 + ch * 8;
        int h = (gcol >> 6) & 15, dd0 = gcol & 63;
        int grow = m0 + ph * 128 + rowrel;
        int b = grow >> 11, s = grow & 2047;
        size_t bh = (size_t)(b * 16 + h);
        *(u16x8*)(qb + (bh * 2048 + s) * 64 + dd0) = v;
      }
    } else if (p == 1) {
#pragma unroll
      for (int it = 0; it < 8; ++it) {
        int ci = it * 512 + tid;
        int rowrel = ci >> 5, ch = ci & 31;
        u16x8 v = *(const u16x8*)(lds + ((rowrel * 512 + ch * 16) ^ ((rowrel & 7) << 4)));
        int gcol = n0 + ch * 8;
        int h = (gcol >> 6) & 15, dd0 = gcol & 63;
        int grow = m0 + ph * 128 + rowrel;
        int b = grow >> 11, s = grow & 2047;
        size_t bh = (size_t)(b * 16 + h);
        int tt = s >> 6, sIn = s & 63;
        int byte = (sIn * 128 + dd0 * 2) ^ ((sIn & 15) << 4);   // 16-slot XOR
        *(u16x8*)((char*)kb + (((size_t)bh * 32 + tt) << 13) + byte) = v;
      }
    } else {
#pragma unroll
      for (int it = 0; it < 8; ++it) {
        int ci = it * 512 + tid;
        int crow = ci >> 4, chh = ci & 15;  // crow = v-col 0..255; chh*8 = s-rel
        u16x8 v = *(const u16x8*)(lds + ((crow * 256 + chh * 16) ^ ((crow & 7) << 4)));
        int gcol = n0 + crow;
        int h = (gcol >> 6) & 15, dd = gcol & 63;
        int grow = m0 + ph * 128 + chh * 8;
        int b = grow >> 11, s = grow & 2047;
        size_t bh = (size_t)(b * 16 + h);
        int tt = s >> 6, sIn0 = s & 63;
        int byte = (dd * 128 + sIn0 * 2) ^ ((dd & 15) << 4);    // 16-slot XOR
        *(u16x8*)((char*)vt + (((size_t)bh * 32 + tt) << 13) + byte) = v;
      }
    }
  }
}

// ---------------------------------------------------------------------------
// Out-projection GEMM: C[8192][1024] fp32 = a_out x wo_t^T.
// 128x128 tile, BK=32, 4 waves, 4-deep 16KB ring (64KB LDS -> 2 blocks/CU),
// counted vmcnt, T2 swizzle via pre-swizzled sources.  Grid 512, XCD-swz.
#define PSTAGE(T)                                                                   \
  {                                                                                 \
    const int pb = ((T) & 3) * 16384;                                               \
    __builtin_amdgcn_global_load_lds(AS1C(gA0), AS3(lds + pb + wid * 1024), 16, 0, 0); \
    __builtin_amdgcn_global_load_lds(AS1C(gA1), AS3(lds + pb + 4096 + wid * 1024), 16, 0, 0); \
    __builtin_amdgcn_global_load_lds(AS1C(gB0), AS3(lds + pb + 8192 + wid * 1024), 16, 0, 0); \
    __builtin_amdgcn_global_load_lds(AS1C(gB1), AS3(lds + pb + 12288 + wid * 1024), 16, 0, 0); \
    gA0 += 32; gA1 += 32; gB0 += 32; gB1 += 32;                                     \
  }

#define PBODY(T, VMSTR, DO_STAGE)                                                   \
  {                                                                                 \
    const int cb = ((T) & 3) * 16384;                                               \
    VMW(VMSTR);                                                                     \
    BAR();                                                                          \
    if (DO_STAGE) PSTAGE((T) + 3);                                                  \
    bf16v8 af[4], bfr[4];                                                           \
    _Pragma("unroll")                                                               \
    for (int i = 0; i < 4; ++i)                                                     \
      af[i] = *(const bf16v8*)(lds + cb + awo + i * 1024);                          \
    _Pragma("unroll")                                                               \
    for (int j = 0; j < 4; ++j)                                                     \
      bfr[j] = *(const bf16v8*)(lds + cb + bwo + j * 1024);                         \
    __builtin_amdgcn_s_setprio(1);                                                  \
    _Pragma("unroll")                                                               \
    for (int i = 0; i < 4; ++i)                                                     \
      _Pragma("unroll")                                                             \
      for (int j = 0; j < 4; ++j)                                                   \
        acc[i][j] = __builtin_amdgcn_mfma_f32_16x16x32_bf16(af[i], bfr[j], acc[i][j], 0, 0, 0); \
    __builtin_amdgcn_s_setprio(0);                                                  \
  }

__global__ __launch_bounds__(256) void gemm128_op(
    const ushort_t* __restrict__ A, const ushort_t* __restrict__ Bt,
    float* __restrict__ Cf) {
  extern __shared__ __align__(16) char lds[];  // 65536 = 4 bufs x (A8K + B8K)
  const int tid = threadIdx.x;
  const int wid = tid >> 6, lane = tid & 63;
  const int g = lane >> 4, lq = lane & 15;
  const int wm = wid >> 1, wn = wid & 1;
  // XCD-aware bijective swizzle (512 % 8 == 0): 64 consecutive wgs per XCD
  const int bid = blockIdx.x;
  const int wg = (bid & 7) * 64 + (bid >> 3);
  const int mb = wg >> 3, nb = wg & 7;
  const int m0 = mb * 128, n0 = nb * 128;

  // swizzled per-lane ds_read col offset: chunk' = g ^ ((row>>1)&3), row&15==lq
  const int co = (g ^ ((lq >> 1) & 3)) * 16;
  const int awo = wm * 4096 + lq * 64 + co;           // A frag base (+i*1024)
  const int bwo = 8192 + wn * 4096 + lq * 64 + co;    // B frag base (+j*1024)

  // stage source pointers (linear copy; sources are pre-swizzled)
  const ushort_t* gA0 = A + (size_t)(m0 + (tid >> 2)) * 1024 + (tid & 3) * 8;
  const ushort_t* gA1 = gA0 + (size_t)64 * 1024;
  const ushort_t* gB0 = Bt + (size_t)(n0 + (tid >> 2)) * 1024 + (tid & 3) * 8;
  const ushort_t* gB1 = gB0 + (size_t)64 * 1024;

  f32x4 acc[4][4] = {};

  // prologue: stage K-tiles 0,1,2 (12 loads/wave in flight)
  PSTAGE(0); PSTAGE(1); PSTAGE(2);

  for (int t = 0; t < 29; ++t) PBODY(t, "8", true);   // t=28 stages tile 31
  PBODY(29, "8", false);
  PBODY(30, "4", false);
  PBODY(31, "0", false);

  // epilogue: direct fp32 stores (16-lane 64B runs)
#pragma unroll
  for (int i = 0; i < 4; ++i)
#pragma unroll
    for (int j = 0; j < 4; ++j)
#pragma unroll
      for (int r = 0; r < 4; ++r) {
        int row = m0 + wm * 64 + i * 16 + g * 4 + r;
        int col = n0 + wn * 64 + j * 16 + lq;
        Cf[(size_t)row * 1024 + col] = acc[i][j][r];
      }
}

// ---------------------------------------------------------------------------
// Flash attention v9: 32x32 swapped-QK^T, in-register P, NO-MAX softmax,
// KVBLK=64, 2-buf 32KB static LDS, grid 1024, counted-vmcnt double-barrier.
// K/V tiles use the 16-slot XOR ((row&15)<<4): 2-way LDS alias = free.
__device__ __forceinline__ void softpack(const f32x16& s0, const f32x16& s1,
                                         float& lsum, bf16v8& pa0, bf16v8& pa1,
                                         bf16v8& pa2, bf16v8& pa3) {
  float e0[16], e1[16];
#pragma unroll
  for (int r = 0; r < 16; ++r) e0[r] = exp2_raw(s0[r]);
#pragma unroll
  for (int r = 0; r < 16; ++r) e1[r] = exp2_raw(s1[r]);
  float ad[16];
#pragma unroll
  for (int r = 0; r < 16; ++r) ad[r] = e0[r] + e1[r];
#pragma unroll
  for (int st = 8; st >= 1; st >>= 1)
#pragma unroll
    for (int r = 0; r < st; ++r) ad[r] += ad[r + st];
  lsum += ad[0];
  unsigned a0 = cvt_pk_bf16(e0[0], e0[1]), b0 = cvt_pk_bf16(e0[4], e0[5]);
  unsigned a1 = cvt_pk_bf16(e0[2], e0[3]), b1 = cvt_pk_bf16(e0[6], e0[7]);
  unsigned a2 = cvt_pk_bf16(e0[8], e0[9]), b2 = cvt_pk_bf16(e0[12], e0[13]);
  unsigned a3 = cvt_pk_bf16(e0[10], e0[11]), b3 = cvt_pk_bf16(e0[14], e0[15]);
  unsigned a4 = cvt_pk_bf16(e1[0], e1[1]), b4 = cvt_pk_bf16(e1[4], e1[5]);
  unsigned a5 = cvt_pk_bf16(e1[2], e1[3]), b5 = cvt_pk_bf16(e1[6], e1[7]);
  unsigned a6 = cvt_pk_bf16(e1[8], e1[9]), b6 = cvt_pk_bf16(e1[12], e1[13]);
  unsigned a7 = cvt_pk_bf16(e1[10], e1[11]), b7 = cvt_pk_bf16(e1[14], e1[15]);
  plswap(a0, b0); plswap(a1, b1); plswap(a2, b2); plswap(a3, b3);
  plswap(a4, b4); plswap(a5, b5); plswap(a6, b6); plswap(a7, b7);
  pa0 = __builtin_bit_cast(bf16v8, u32x4{a0, a1, b0, b1});  // kv  0..15
  pa1 = __builtin_bit_cast(bf16v8, u32x4{a2, a3, b2, b3});  // kv 16..31
  pa2 = __builtin_bit_cast(bf16v8, u32x4{a4, a5, b4, b5});  // kv 32..47
  pa3 = __builtin_bit_cast(bf16v8, u32x4{a6, a7, b6, b7});  // kv 48..63
}

#define MFMA32(a, b, c) __builtin_amdgcn_mfma_f32_32x32x16_bf16(a, b, c, 0, 0, 0)

#define ASTAGE(T)                                                                   \
  {                                                                                 \
    const int pb = ((T) & 1) * 16384;                                               \
    const char* ks = kbase + ((size_t)(T) << 13);                                   \
    const char* vs = vbase + ((size_t)(T) << 13);                                   \
    _Pragma("unroll")                                                               \
    for (int j = 0; j < 2; ++j) {                                                   \
      __builtin_amdgcn_global_load_lds(AS1C(ks + w * 2048 + j * 1024 + lane * 16),  \
                                       AS3(smem + pb + w * 2048 + j * 1024), 16, 0, 0); \
      __builtin_amdgcn_global_load_lds(AS1C(vs + w * 2048 + j * 1024 + lane * 16),  \
                                       AS3(smem + pb + 8192 + w * 2048 + j * 1024), 16, 0, 0); \
    }                                                                               \
  }

#define ACOMPUTE(T)                                                                 \
  {                                                                                 \
    const char* bk = smem + ((T) & 1) * 16384;                                      \
    bf16v8 kf0[4], kf1[4], vfr[2][4];                                               \
    _Pragma("unroll")                                                               \
    for (int c = 0; c < 4; ++c) {                                                   \
      kf0[c] = *(const bf16v8*)(bk + addr4[c]);                                     \
      kf1[c] = *(const bf16v8*)(bk + addr4[c] + 4096);                              \
    }                                                                               \
    _Pragma("unroll")                                                               \
    for (int nb = 0; nb < 2; ++nb)                                                  \
      _Pragma("unroll")                                                             \
      for (int ks2 = 0; ks2 < 4; ++ks2)                                             \
        vfr[nb][ks2] = *(const bf16v8*)(bk + addr4[ks2] + 8192 + nb * 4096);        \
    f32x16 s0 = {}, s1 = {};                                                        \
    __builtin_amdgcn_s_setprio(1);                                                  \
    _Pragma("unroll")                                                               \
    for (int c = 0; c < 4; ++c) {                                                   \
      s0 = MFMA32(kf0[c], qf[c], s0);                                               \
      s1 = MFMA32(kf1[c], qf[c], s1);                                               \
    }                                                                               \
    __builtin_amdgcn_s_setprio(0);                                                  \
    bf16v8 pa0, pa1, pa2, pa3;                                                      \
    softpack(s0, s1, lsum, pa0, pa1, pa2, pa3);                                     \
    __builtin_amdgcn_s_setprio(1);                                                  \
    _Pragma("unroll")                                                               \
    for (int nb = 0; nb < 2; ++nb) {                                                \
      oa[nb] = MFMA32(pa0, vfr[nb][0], oa[nb]);                                     \
      oa[nb] = MFMA32(pa1, vfr[nb][1], oa[nb]);                                     \
      oa[nb] = MFMA32(pa2, vfr[nb][2], oa[nb]);                                     \
      oa[nb] = MFMA32(pa3, vfr[nb][3], oa[nb]);                                     \
    }                                                                               \
    __builtin_amdgcn_s_setprio(0);                                                  \
  }

__global__ __launch_bounds__(256) void attn_kernel(const ushort_t* __restrict__ qb,
                                                   const ushort_t* __restrict__ kt,
                                                   const ushort_t* __restrict__ vt,
                                                   ushort_t* __restrict__ aout) {
  __shared__ __align__(16) char smem[32768];
  __shared__ float cbuf[4][32];
  const int tid = threadIdx.x;
  const int w = tid >> 6, lane = tid & 63;
  const int hi = lane >> 5, l31 = lane & 31;
  // XCD swizzle: the 16 blocks of one bh all share blockIdx%8 -> same XCD L2
  const int bidx = blockIdx.x;           // grid = 1024
  const int xcd = bidx & 7, slot = bidx >> 3;
  const int bh = xcd + 8 * (slot >> 4);  // 0..63
  const int qt = (slot & 15) * 4 + w;    // 0..63 (32-row q tile)
  const char* kbase = (const char*)kt + ((size_t)bh << 18);  // 32 tiles * 8KB
  const char* vbase = (const char*)vt + ((size_t)bh << 18);
  const ushort_t* Qp = qb + (size_t)bh * (S_ * 64) + qt * 32 * 64;

  // Q B-frags: lane holds Q[q=l31][dk = c*16 + hi*8 + e]
  bf16v8 qf[4];
#pragma unroll
  for (int c = 0; c < 4; ++c)
    qf[c] = *(const bf16v8*)(Qp + l31 * 64 + c * 16 + hi * 8);

  // loop-invariant swizzled LDS byte offsets (row = l31, colByte = c*32+hi*16)
  // 16-slot XOR: 32 lanes -> 16 slots = 2-way = free (m136)
  int addr4[4];
#pragma unroll
  for (int c = 0; c < 4; ++c)
    addr4[c] = (l31 * 128 + c * 32 + hi * 16) ^ ((l31 & 15) << 4);

  f32x16 oa[2] = {};            // O[q][dv], dv-blocks of 32
  float lsum = 0.f;             // own-half row sum; cross-half shfl at end

  // prologue: stage tile 0 into buffer 0 (4 loads/wave)
  ASTAGE(0);

#pragma unroll 2
  for (int t = 0; t < 31; ++t) {
    BAR();            // all waves done reading buf[(t+1)&1] (during iter t-1)
    ASTAGE(t + 1);    // 4 loads into buf[(t+1)&1]
    VMW("4");         // own tile-t loads landed; t+1's stay in flight
    BAR();            // all waves' tile-t loads landed
    ACOMPUTE(t);
  }
  BAR();
  VMW("0");           // last tile: drain (nothing left to overlap)
  BAR();
  ACOMPUTE(31);

  // cross-half row-sum (deferred from the loop), then normalize via LDS
  // broadcast-transpose. ob region = buf0 (0..16KB): last compute used buf1.
  lsum += __shfl_xor(lsum, 32);
  ushort_t* ob = (ushort_t*)(smem + w * 4096);
  cbuf[w][l31] = 1.0f / lsum;
  asm volatile("s_waitcnt lgkmcnt(0)" ::: "memory");
#pragma unroll
  for (int rq = 0; rq < 4; ++rq) {
    f32x4 c4 = *(const f32x4*)&cbuf[w][8 * rq + 4 * hi];
#pragma unroll
    for (int j = 0; j < 4; ++j) {
      int row = 8 * rq + 4 * hi + j;
#pragma unroll
      for (int nb = 0; nb < 2; ++nb)
        ob[row * 64 + nb * 32 + l31] = f2bf(oa[nb][4 * rq + j] * c4[j]);
    }
  }
  asm volatile("s_waitcnt lgkmcnt(0)" ::: "memory");
  const int row = lane >> 1, hf = lane & 1;
  const int b = bh >> 4, h = bh & 15;
  const int rowg = b * 2048 + qt * 32 + row;     // global (b,s) row
  const int sx = (rowg >> 1) & 3;                // out-proj pre-swizzle
  size_t rbase = (size_t)rowg * 1024;
#pragma unroll
  for (int i = 0; i < 4; ++i) {
    bf16v8 v = *(const bf16v8*)&ob[row * 64 + hf * 32 + i * 8];
    int c = h * 8 + hf * 4 + i;                  // 16B-chunk index in row
    *(bf16v8*)(aout + rbase + (size_t)((c ^ sx) * 8)) = v;
  }
}

// ---------------------------------------------------------------------------
extern "C" void kernel_launch(void* const* d_in, const int* in_sizes, int n_in,
                              void* d_out, int out_size, void* d_ws, size_t ws_size,
                              hipStream_t stream) {
  const float* x = (const float*)d_in[0];
  const float* Wq = (const float*)d_in[1];
  const float* Wk = (const float*)d_in[2];
  const float* Wv = (const float*)d_in[3];
  const float* Wo = (const float*)d_in[4];
  float* out = (float*)d_out;

  // workspace layout (bytes)
  char* ws = (char*)d_ws;
  constexpr size_t OFF_XB = 0;                       // 16 MB  x bf16 pre-swz
  constexpr size_t OFF_WQKV = 16777216;              // 6 MB   [3][H][dk][D] pre-swz
  constexpr size_t OFF_WO = 23068672;                // 2 MB   [N][K] pre-swz
  constexpr size_t OFF_Q = 25165824;                 // 16 MB  [BH][S][64] raw
  constexpr size_t OFF_K = 41943040;                 // 16 MB  K tiled+attn-swz
  constexpr size_t OFF_V = 58720256;                 // 16 MB  V tiled+attn-swz
  constexpr size_t OFF_AO = 75497472;                // 16 MB  [8192][1024] pre-swz
  constexpr size_t WS_NEEDED = 92274688;
  if (ws_size < WS_NEEDED) return;  // refuse to scribble OOB

  ushort_t* xb = (ushort_t*)(ws + OFF_XB);
  ushort_t* wqkv_t = (ushort_t*)(ws + OFF_WQKV);
  ushort_t* wo_t = (ushort_t*)(ws + OFF_WO);
  ushort_t* q_buf = (ushort_t*)(ws + OFF_Q);
  ushort_t* k_t = (ushort_t*)(ws + OFF_K);
  ushort_t* v_t = (ushort_t*)(ws + OFF_V);
  ushort_t* a_out = (ushort_t*)(ws + OFF_AO);

  cast_x_kernel<<<(M_ * D_ / 8) / 256, 256, 0, stream>>>(x, xb);
  prep_wqkv_kernel<<<192, 256, 0, stream>>>(Wq, Wk, Wv, wqkv_t);
  prep_wo_kernel<<<64, 256, 0, stream>>>(Wo, wo_t);

  gemm256_qkv<<<(M_ / 256) * (NQKV_ / 256), 512, 65536, stream>>>(
      xb, wqkv_t, q_buf, k_t, v_t);

  attn_kernel<<<1024, 256, 0, stream>>>(q_buf, k_t, v_t, a_out);

  gemm128_op<<<(M_ / 128) * (D_ / 128), 256, 65536, stream>>>(a_out, wo_t, out);
}

// Round 16
// 193.295 us; speedup vs baseline: 1.0504x; 1.0266x over previous
//
#include <hip/hip_runtime.h>
#include <hip/hip_bf16.h>
#include <cstdint>
#include <cstddef>

// ---------------------------------------------------------------------------
// MHA: x[4,2048,1024] -> out[4,2048,1024], fp32 I/O, bf16 MFMA internals.
// ---------------------------------------------------------------------------

typedef __attribute__((ext_vector_type(8))) __bf16 bf16v8;
typedef __attribute__((ext_vector_type(4))) float f32x4;
typedef __attribute__((ext_vector_type(16))) float f32x16;
typedef __attribute__((ext_vector_type(8))) unsigned short u16x8;
typedef __attribute__((ext_vector_type(4))) unsigned u32x4;
typedef unsigned short ushort_t;

#define AS3(p) ((__attribute__((address_space(3))) void*)(p))
#define AS1C(p) ((const __attribute__((address_space(1))) void*)(p))

__device__ __forceinline__ ushort_t f2bf(float f) {
  unsigned u = __builtin_bit_cast(unsigned, f);
  unsigned r = u + 0x7FFFu + ((u >> 16) & 1u);   // RNE
  return (ushort_t)(r >> 16);
}

__device__ __forceinline__ unsigned cvt_pk_bf16(float lo, float hi) {
  unsigned r;
  asm("v_cvt_pk_bf16_f32 %0, %1, %2" : "=v"(r) : "v"(lo), "v"(hi));
  return r;
}

// v_permlane32_swap_b32 vdst, vsrc : vdst.hi <-> vsrc.lo (lane i+32 <-> lane i)
__device__ __forceinline__ void plswap(unsigned& x, unsigned& y) {
  asm("v_permlane32_swap_b32 %0, %1" : "+v"(x), "+v"(y));
}

// raw v_exp_f32 (2^x). Scores are bounded (|log2-score| < ~40): no overflow;
// subnormal flush-to-zero is the correct limit for vanished softmax terms.
__device__ __forceinline__ float exp2_raw(float x) {
  float r;
  asm("v_exp_f32 %0, %1" : "=v"(r) : "v"(x));
  return r;
}

constexpr int B_ = 4, S_ = 2048, D_ = 1024, H_ = 16, DK_ = 64;
constexpr int M_ = B_ * S_;          // 8192 rows (b,s)
constexpr int NQKV_ = 3 * H_ * DK_;  // 3072
// fold 1/sqrt(dk) * log2(e) into W_Q so scores are in log2-space
constexpr float QSCALE = 0.125f * 1.44269504088896f;

// ---------------------------------------------------------------------------
// x fp32 -> bf16, 8 elems/thread.  Output PRE-SWIZZLED for the GEMMs:
// 16B chunk index i goes to i ^ ((i>>8)&3)  (== col-chunk ^ (row>>1)&3).
__global__ __launch_bounds__(256) void cast_x_kernel(const float* __restrict__ x,
                                                     ushort_t* __restrict__ xb) {
  size_t i = (size_t)blockIdx.x * 256 + threadIdx.x;  // 16B-chunk index
  const float4* px = (const float4*)(x + i * 8);
  float4 a = px[0], b = px[1];
  u16x8 v;
  v[0] = f2bf(a.x); v[1] = f2bf(a.y); v[2] = f2bf(a.z); v[3] = f2bf(a.w);
  v[4] = f2bf(b.x); v[5] = f2bf(b.y); v[6] = f2bf(b.z); v[7] = f2bf(b.w);
  size_t di = i ^ ((i >> 8) & 3);
  *(u16x8*)(xb + di * 8) = v;
}

// ---------------------------------------------------------------------------
// W_Q/W_K/W_V [H][D][dk] f32 -> wqkv_t [p][h][dk][D] bf16 (B^T layout,
// pre-swizzled: elem idx -> idx ^ (((idx>>11)&3)<<3), == chunk ^ (dk>>1)&3).
// LDS-tiled transpose with coalesced reads/writes.
__global__ __launch_bounds__(256) void prep_wqkv_kernel(const float* __restrict__ Wq,
                                                        const float* __restrict__ Wk,
                                                        const float* __restrict__ Wv,
                                                        ushort_t* __restrict__ dst) {
  __shared__ ushort_t lt[64 * 264];
  const int t = threadIdx.x;
  const int blk = blockIdx.x;            // 192 = p(3) x h(16) x dchunk(4)
  const int p = blk >> 6;
  const int rem = blk & 63;
  const int h = rem >> 2, d0 = (rem & 3) << 8;
  const float* W = (p == 0) ? Wq : ((p == 1) ? Wk : Wv);
  const float sc = (p == 0) ? QSCALE : 1.0f;
  const int rt = t >> 4, cq = (t & 15) << 2;
#pragma unroll
  for (int it = 0; it < 16; ++it) {
    int r = it * 16 + rt;                // d-offset 0..255
    float4 v = *(const float4*)(W + (h << 16) + (size_t)(d0 + r) * 64 + cq);
    lt[(cq + 0) * 264 + r] = f2bf(v.x * sc);
    lt[(cq + 1) * 264 + r] = f2bf(v.y * sc);
    lt[(cq + 2) * 264 + r] = f2bf(v.z * sc);
    lt[(cq + 3) * 264 + r] = f2bf(v.w * sc);
  }
  __syncthreads();
  const int c8 = t & 31;                 // 16B chunk within the 256-d segment
#pragma unroll
  for (int it = 0; it < 8; ++it) {
    int dk = it * 8 + (t >> 5);
    u16x8 v = *(const u16x8*)&lt[dk * 264 + c8 * 8];
    int s = (dk >> 1) & 3;
    *(u16x8*)(dst + ((p << 20) | (h << 16) | (dk << 10)) + d0 + ((c8 ^ s) << 3)) = v;
  }
}

// W_O [K=1024][N=1024] f32 -> wo_t [N][K] bf16 (pre-swizzled, chunk ^ (n>>1)&3).
__global__ __launch_bounds__(256) void prep_wo_kernel(const float* __restrict__ Wo,
                                                      ushort_t* __restrict__ dst) {
  __shared__ ushort_t lt[64 * 264];
  const int t = threadIdx.x;
  const int n0 = (blockIdx.x >> 2) << 6;   // 16 n-tiles of 64
  const int k0 = (blockIdx.x & 3) << 8;    // 4 k-tiles of 256
  const int rt = t >> 4, nq = (t & 15) << 2;
#pragma unroll
  for (int it = 0; it < 16; ++it) {
    int kr = it * 16 + rt;                 // k-offset 0..255
    float4 v = *(const float4*)(Wo + (size_t)(k0 + kr) * 1024 + n0 + nq);
    lt[(nq + 0) * 264 + kr] = f2bf(v.x);
    lt[(nq + 1) * 264 + kr] = f2bf(v.y);
    lt[(nq + 2) * 264 + kr] = f2bf(v.z);
    lt[(nq + 3) * 264 + kr] = f2bf(v.w);
  }
  __syncthreads();
  const int c8 = t & 31;
#pragma unroll
  for (int it = 0; it < 8; ++it) {
    int nr = it * 8 + (t >> 5);
    u16x8 v = *(const u16x8*)&lt[nr * 264 + c8 * 8];
    int n = n0 + nr;
    int s = (n >> 1) & 3;
    *(u16x8*)(dst + (size_t)n * 1024 + k0 + ((c8 ^ s) << 3)) = v;
  }
}

// ---------------------------------------------------------------------------
// 256x256 QKV GEMM (r13 config, the measured optimum): BK=32, 8 waves (2Mx4N),
// 4-deep LDS ring (4 x 32KB = 128KB), counted vmcnt (prefetch 3, steady
// VMW(8)), raw s_barrier per tile, T2 swizzle via pre-swizzled sources (#21).
// Epilogue: C staged in the dead ring LDS (V third transposed), 16B coalesced
// scatter; K/V attn-tiles use the 16-slot XOR ((row&15)<<4): 2-way = free.
#define VMW(N) asm volatile("s_waitcnt vmcnt(" N ")" ::: "memory")
#define BAR() asm volatile("s_barrier" ::: "memory")

#define STAGE3(T)                                                                   \
  {                                                                                 \
    const int pb = (((T) + 3) & 3) * 32768;                                         \
    __builtin_amdgcn_global_load_lds(AS1C(gA0), AS3(lds + pb + wid * 1024), 16, 0, 0); \
    __builtin_amdgcn_global_load_lds(AS1C(gA1), AS3(lds + pb + 8192 + wid * 1024), 16, 0, 0); \
    __builtin_amdgcn_global_load_lds(AS1C(gB0), AS3(lds + pb + 16384 + wid * 1024), 16, 0, 0); \
    __builtin_amdgcn_global_load_lds(AS1C(gB1), AS3(lds + pb + 24576 + wid * 1024), 16, 0, 0); \
    gA0 += 32; gA1 += 32; gB0 += 32; gB1 += 32;                                     \
  }

#define TILE_BODY(T, VMSTR, DO_STAGE)                                               \
  {                                                                                 \
    const int cb = ((T) & 3) * 32768;                                               \
    VMW(VMSTR);                                                                     \
    BAR();                                                                          \
    if (DO_STAGE) STAGE3(T);                                                        \
    bf16v8 af[8], bfr[4];                                                           \
    _Pragma("unroll")                                                               \
    for (int i = 0; i < 8; ++i)                                                     \
      af[i] = *(const bf16v8*)(lds + cb + awo + i * 1024);                          \
    _Pragma("unroll")                                                               \
    for (int j = 0; j < 4; ++j)                                                     \
      bfr[j] = *(const bf16v8*)(lds + cb + bwo + j * 1024);                         \
    __builtin_amdgcn_s_setprio(1);                                                  \
    _Pragma("unroll")                                                               \
    for (int i = 0; i < 8; ++i)                                                     \
      _Pragma("unroll")                                                             \
      for (int j = 0; j < 4; ++j)                                                   \
        acc[i][j] = __builtin_amdgcn_mfma_f32_16x16x32_bf16(af[i], bfr[j], acc[i][j], 0, 0, 0); \
    __builtin_amdgcn_s_setprio(0);                                                  \
  }

__global__ __launch_bounds__(512) void gemm256_qkv(
    const ushort_t* __restrict__ A, const ushort_t* __restrict__ Bt,
    ushort_t* __restrict__ qb, ushort_t* __restrict__ kb, ushort_t* __restrict__ vt) {
  extern __shared__ __align__(16) char lds[];  // 131072 B = 4 bufs x (A16K+B16K)
  const int tid = threadIdx.x;
  const int wid = tid >> 6, lane = tid & 63;
  const int g = lane >> 4, lq = lane & 15;
  const int wm = wid >> 2, wn = wid & 3;
  // XCD-aware bijective swizzle (384 % 8 == 0): 48 consecutive wgs per XCD
  const int bid = blockIdx.x;
  const int wg = (bid & 7) * 48 + (bid >> 3);
  const int mb = wg / 12, nb = wg % 12;
  const int m0 = mb * 256, n0 = nb * 256;

  // swizzled per-lane ds_read col offset: chunk' = g ^ ((row>>1)&3), row&15==lq
  const int co = (g ^ ((lq >> 1) & 3)) * 16;
  const int awo = wm * 8192 + lq * 64 + co;            // A frag base (+i*1024)
  const int bwo = 16384 + wn * 4096 + lq * 64 + co;    // B frag base (+j*1024)

  // stage source pointers (linear copy; sources are pre-swizzled)
  const ushort_t* gA0 = A + (size_t)(m0 + (tid >> 2)) * 1024 + (tid & 3) * 8;
  const ushort_t* gA1 = gA0 + (size_t)128 * 1024;
  const ushort_t* gB0 = Bt + (size_t)(n0 + (tid >> 2)) * 1024 + (tid & 3) * 8;
  const ushort_t* gB1 = gB0 + (size_t)128 * 1024;

  f32x4 acc[8][4] = {};

  // prologue: stage K-tiles 0,1,2 (12 loads/wave in flight)
  STAGE3(-3); STAGE3(-2); STAGE3(-1);

  for (int t = 0; t < 28; ++t) TILE_BODY(t, "8", true);
  TILE_BODY(28, "8", true);   // stages tile 31
  TILE_BODY(29, "8", false);
  TILE_BODY(30, "4", false);
  TILE_BODY(31, "0", false);

  // ---- epilogue: acc -> LDS (bf16 C-tile; V third transposed) ----
  asm volatile("s_waitcnt lgkmcnt(0)" ::: "memory");
  BAR();
  const int p = n0 >> 10;  // uniform per block (256 | 1024)
  if (p == 2) {
    // transposed: element (row s, col v) at byte (col*512 + row*2) ^ ((col&7)<<4)
#pragma unroll
    for (int i = 0; i < 8; ++i)
#pragma unroll
      for (int j = 0; j < 4; ++j) {
        int col = wn * 64 + j * 16 + lq;
        int swz = (col & 7) << 4;
#pragma unroll
        for (int r = 0; r < 4; ++r) {
          int row = wm * 128 + i * 16 + g * 4 + r;
          *(ushort_t*)(lds + ((col * 512 + row * 2) ^ swz)) = f2bf(acc[i][j][r]);
        }
      }
  } else {
    // row-major: element (row,col) at byte (row*512 + col*2) ^ ((row&7)<<4)
#pragma unroll
    for (int i = 0; i < 8; ++i)
#pragma unroll
      for (int j = 0; j < 4; ++j) {
        int col = wn * 64 + j * 16 + lq;
#pragma unroll
        for (int r = 0; r < 4; ++r) {
          int row = wm * 128 + i * 16 + g * 4 + r;
          *(ushort_t*)(lds + ((row * 512 + col * 2) ^ ((row & 7) << 4))) = f2bf(acc[i][j][r]);
        }
      }
  }
  asm volatile("s_waitcnt lgkmcnt(0)" ::: "memory");
  BAR();

  // ---- coalesced 16B stores: 16 chunks/thread ----
  if (p == 0) {
#pragma unroll
    for (int it = 0; it < 16; ++it) {
      int ci = it * 512 + tid;
      int row = ci >> 5, ch = ci & 31;
      u16x8 v = *(const u16x8*)(lds + ((row * 512 + ch * 16) ^ ((row & 7) << 4)));
      int gcol = n0 + ch * 8;
      int h = (gcol >> 6) & 15, dd0 = gcol & 63;
      int grow = m0 + row;
      int b = grow >> 11, s = grow & 2047;
      size_t bh = (size_t)(b * 16 + h);
      *(u16x8*)(qb + (bh * 2048 + s) * 64 + dd0) = v;
    }
  } else if (p == 1) {
#pragma unroll
    for (int it = 0; it < 16; ++it) {
      int ci = it * 512 + tid;
      int row = ci >> 5, ch = ci & 31;
      u16x8 v = *(const u16x8*)(lds + ((row * 512 + ch * 16) ^ ((row & 7) << 4)));
      int gcol = n0 + ch * 8;
      int h = (gcol >> 6) & 15, dd0 = gcol & 63;
      int grow = m0 + row;
      int b = grow >> 11, s = grow & 2047;
      size_t bh = (size_t)(b * 16 + h);
      int tt = s >> 6, sIn = s & 63;
      int byte = (sIn * 128 + dd0 * 2) ^ ((sIn & 15) << 4);   // 16-slot XOR
      *(u16x8*)((char*)kb + (((size_t)bh * 32 + tt) << 13) + byte) = v;
    }
  } else {
#pragma unroll
    for (int it = 0; it < 16; ++it) {
      int ci = it * 512 + tid;
      int crow = ci >> 5, ch = ci & 31;   // crow = v-col index; ch*8 = s-chunk
      u16x8 v = *(const u16x8*)(lds + ((crow * 512 + ch * 16) ^ ((crow & 7) << 4)));
      int gcol = n0 + crow;
      int h = (gcol >> 6) & 15, dd = gcol & 63;
      int grow = m0 + ch * 8;
      int b = grow >> 11, s = grow & 2047;
      size_t bh = (size_t)(b * 16 + h);
      int tt = s >> 6, sIn0 = s & 63;
      int byte = (dd * 128 + sIn0 * 2) ^ ((dd & 15) << 4);    // 16-slot XOR
      *(u16x8*)((char*)vt + (((size_t)bh * 32 + tt) << 13) + byte) = v;
    }
  }
}

// ---------------------------------------------------------------------------
// Out-projection GEMM: C[8192][1024] fp32 = a_out x wo_t^T.
// 128x128 tile, BK=32, 4 waves, 4-deep 16KB ring (64KB LDS -> 2 blocks/CU),
// counted vmcnt, T2 swizzle via pre-swizzled sources.  Grid 512, XCD-swz.
#define PSTAGE(T)                                                                   \
  {                                                                                 \
    const int pb = ((T) & 3) * 16384;                                               \
    __builtin_amdgcn_global_load_lds(AS1C(gA0), AS3(lds + pb + wid * 1024), 16, 0, 0); \
    __builtin_amdgcn_global_load_lds(AS1C(gA1), AS3(lds + pb + 4096 + wid * 1024), 16, 0, 0); \
    __builtin_amdgcn_global_load_lds(AS1C(gB0), AS3(lds + pb + 8192 + wid * 1024), 16, 0, 0); \
    __builtin_amdgcn_global_load_lds(AS1C(gB1), AS3(lds + pb + 12288 + wid * 1024), 16, 0, 0); \
    gA0 += 32; gA1 += 32; gB0 += 32; gB1 += 32;                                     \
  }

#define PBODY(T, VMSTR, DO_STAGE)                                                   \
  {                                                                                 \
    const int cb = ((T) & 3) * 16384;                                               \
    VMW(VMSTR);                                                                     \
    BAR();                                                                          \
    if (DO_STAGE) PSTAGE((T) + 3);                                                  \
    bf16v8 af[4], bfr[4];                                                           \
    _Pragma("unroll")                                                               \
    for (int i = 0; i < 4; ++i)                                                     \
      af[i] = *(const bf16v8*)(lds + cb + awo + i * 1024);                          \
    _Pragma("unroll")                                                               \
    for (int j = 0; j < 4; ++j)                                                     \
      bfr[j] = *(const bf16v8*)(lds + cb + bwo + j * 1024);                         \
    __builtin_amdgcn_s_setprio(1);                                                  \
    _Pragma("unroll")                                                               \
    for (int i = 0; i < 4; ++i)                                                     \
      _Pragma("unroll")                                                             \
      for (int j = 0; j < 4; ++j)                                                   \
        acc[i][j] = __builtin_amdgcn_mfma_f32_16x16x32_bf16(af[i], bfr[j], acc[i][j], 0, 0, 0); \
    __builtin_amdgcn_s_setprio(0);                                                  \
  }

__global__ __launch_bounds__(256) void gemm128_op(
    const ushort_t* __restrict__ A, const ushort_t* __restrict__ Bt,
    float* __restrict__ Cf) {
  extern __shared__ __align__(16) char lds[];  // 65536 = 4 bufs x (A8K + B8K)
  const int tid = threadIdx.x;
  const int wid = tid >> 6, lane = tid & 63;
  const int g = lane >> 4, lq = lane & 15;
  const int wm = wid >> 1, wn = wid & 1;
  // XCD-aware bijective swizzle (512 % 8 == 0): 64 consecutive wgs per XCD
  const int bid = blockIdx.x;
  const int wg = (bid & 7) * 64 + (bid >> 3);
  const int mb = wg >> 3, nb = wg & 7;
  const int m0 = mb * 128, n0 = nb * 128;

  // swizzled per-lane ds_read col offset: chunk' = g ^ ((row>>1)&3), row&15==lq
  const int co = (g ^ ((lq >> 1) & 3)) * 16;
  const int awo = wm * 4096 + lq * 64 + co;           // A frag base (+i*1024)
  const int bwo = 8192 + wn * 4096 + lq * 64 + co;    // B frag base (+j*1024)

  // stage source pointers (linear copy; sources are pre-swizzled)
  const ushort_t* gA0 = A + (size_t)(m0 + (tid >> 2)) * 1024 + (tid & 3) * 8;
  const ushort_t* gA1 = gA0 + (size_t)64 * 1024;
  const ushort_t* gB0 = Bt + (size_t)(n0 + (tid >> 2)) * 1024 + (tid & 3) * 8;
  const ushort_t* gB1 = gB0 + (size_t)64 * 1024;

  f32x4 acc[4][4] = {};

  // prologue: stage K-tiles 0,1,2 (12 loads/wave in flight)
  PSTAGE(0); PSTAGE(1); PSTAGE(2);

  for (int t = 0; t < 29; ++t) PBODY(t, "8", true);   // t=28 stages tile 31
  PBODY(29, "8", false);
  PBODY(30, "4", false);
  PBODY(31, "0", false);

  // epilogue: direct fp32 stores (16-lane 64B runs)
#pragma unroll
  for (int i = 0; i < 4; ++i)
#pragma unroll
    for (int j = 0; j < 4; ++j)
#pragma unroll
      for (int r = 0; r < 4; ++r) {
        int row = m0 + wm * 64 + i * 16 + g * 4 + r;
        int col = n0 + wn * 64 + j * 16 + lq;
        Cf[(size_t)row * 1024 + col] = acc[i][j][r];
      }
}

// ---------------------------------------------------------------------------
// Flash attention v10: 32x32 swapped-QK^T, in-register P, NO-MAX softmax
// with the row-sum computed BY THE MFMA PIPE (ones B-fragment): the sum
// Sum_kv P[q][kv] lands in an f32x16 accumulator with the SAME register
// layout as the O accumulator -> normalization is a per-register multiply
// (no VALU add-tree, no cross-half shfl, no LDS broadcast-transpose).
// KVBLK=64, 2-buf 32KB static LDS, grid 1024, counted-vmcnt double-barrier.
// K/V tiles use the 16-slot XOR ((row&15)<<4): 2-way LDS alias = free.
__device__ __forceinline__ void softpack(const f32x16& s0, const f32x16& s1,
                                         bf16v8& pa0, bf16v8& pa1,
                                         bf16v8& pa2, bf16v8& pa3) {
  float e0[16], e1[16];
#pragma unroll
  for (int r = 0; r < 16; ++r) e0[r] = exp2_raw(s0[r]);
#pragma unroll
  for (int r = 0; r < 16; ++r) e1[r] = exp2_raw(s1[r]);
  unsigned a0 = cvt_pk_bf16(e0[0], e0[1]), b0 = cvt_pk_bf16(e0[4], e0[5]);
  unsigned a1 = cvt_pk_bf16(e0[2], e0[3]), b1 = cvt_pk_bf16(e0[6], e0[7]);
  unsigned a2 = cvt_pk_bf16(e0[8], e0[9]), b2 = cvt_pk_bf16(e0[12], e0[13]);
  unsigned a3 = cvt_pk_bf16(e0[10], e0[11]), b3 = cvt_pk_bf16(e0[14], e0[15]);
  unsigned a4 = cvt_pk_bf16(e1[0], e1[1]), b4 = cvt_pk_bf16(e1[4], e1[5]);
  unsigned a5 = cvt_pk_bf16(e1[2], e1[3]), b5 = cvt_pk_bf16(e1[6], e1[7]);
  unsigned a6 = cvt_pk_bf16(e1[8], e1[9]), b6 = cvt_pk_bf16(e1[12], e1[13]);
  unsigned a7 = cvt_pk_bf16(e1[10], e1[11]), b7 = cvt_pk_bf16(e1[14], e1[15]);
  plswap(a0, b0); plswap(a1, b1); plswap(a2, b2); plswap(a3, b3);
  plswap(a4, b4); plswap(a5, b5); plswap(a6, b6); plswap(a7, b7);
  pa0 = __builtin_bit_cast(bf16v8, u32x4{a0, a1, b0, b1});  // kv  0..15
  pa1 = __builtin_bit_cast(bf16v8, u32x4{a2, a3, b2, b3});  // kv 16..31
  pa2 = __builtin_bit_cast(bf16v8, u32x4{a4, a5, b4, b5});  // kv 32..47
  pa3 = __builtin_bit_cast(bf16v8, u32x4{a6, a7, b6, b7});  // kv 48..63
}

#define MFMA32(a, b, c) __builtin_amdgcn_mfma_f32_32x32x16_bf16(a, b, c, 0, 0, 0)

#define ASTAGE(T)                                                                   \
  {                                                                                 \
    const int pb = ((T) & 1) * 16384;                                               \
    const char* ks = kbase + ((size_t)(T) << 13);                                   \
    const char* vs = vbase + ((size_t)(T) << 13);                                   \
    _Pragma("unroll")                                                               \
    for (int j = 0; j < 2; ++j) {                                                   \
      __builtin_amdgcn_global_load_lds(AS1C(ks + w * 2048 + j * 1024 + lane * 16),  \
                                       AS3(smem + pb + w * 2048 + j * 1024), 16, 0, 0); \
      __builtin_amdgcn_global_load_lds(AS1C(vs + w * 2048 + j * 1024 + lane * 16),  \
                                       AS3(smem + pb + 8192 + w * 2048 + j * 1024), 16, 0, 0); \
    }                                                                               \
  }

#define ACOMPUTE(T)                                                                 \
  {                                                                                 \
    const char* bk = smem + ((T) & 1) * 16384;                                      \
    bf16v8 kf0[4], kf1[4], vfr[2][4];                                               \
    _Pragma("unroll")                                                               \
    for (int c = 0; c < 4; ++c) {                                                   \
      kf0[c] = *(const bf16v8*)(bk + addr4[c]);                                     \
      kf1[c] = *(const bf16v8*)(bk + addr4[c] + 4096);                              \
    }                                                                               \
    _Pragma("unroll")                                                               \
    for (int nb = 0; nb < 2; ++nb)                                                  \
      _Pragma("unroll")                                                             \
      for (int ks2 = 0; ks2 < 4; ++ks2)                                             \
        vfr[nb][ks2] = *(const bf16v8*)(bk + addr4[ks2] + 8192 + nb * 4096);        \
    f32x16 s0 = {}, s1 = {};                                                        \
    __builtin_amdgcn_s_setprio(1);                                                  \
    _Pragma("unroll")                                                               \
    for (int c = 0; c < 4; ++c) {                                                   \
      s0 = MFMA32(kf0[c], qf[c], s0);                                               \
      s1 = MFMA32(kf1[c], qf[c], s1);                                               \
    }                                                                               \
    __builtin_amdgcn_s_setprio(0);                                                  \
    bf16v8 pa0, pa1, pa2, pa3;                                                      \
    softpack(s0, s1, pa0, pa1, pa2, pa3);                                           \
    __builtin_amdgcn_s_setprio(1);                                                  \
    _Pragma("unroll")                                                               \
    for (int nb = 0; nb < 2; ++nb) {                                                \
      oa[nb] = MFMA32(pa0, vfr[nb][0], oa[nb]);                                     \
      oa[nb] = MFMA32(pa1, vfr[nb][1], oa[nb]);                                     \
      oa[nb] = MFMA32(pa2, vfr[nb][2], oa[nb]);                                     \
      oa[nb] = MFMA32(pa3, vfr[nb][3], oa[nb]);                                     \
    }                                                                               \
    oas = MFMA32(pa0, onesf, oas);                                                  \
    oas = MFMA32(pa1, onesf, oas);                                                  \
    oas = MFMA32(pa2, onesf, oas);                                                  \
    oas = MFMA32(pa3, onesf, oas);                                                  \
    __builtin_amdgcn_s_setprio(0);                                                  \
  }

__global__ __launch_bounds__(256) void attn_kernel(const ushort_t* __restrict__ qb,
                                                   const ushort_t* __restrict__ kt,
                                                   const ushort_t* __restrict__ vt,
                                                   ushort_t* __restrict__ aout) {
  __shared__ __align__(16) char smem[32768];
  const int tid = threadIdx.x;
  const int w = tid >> 6, lane = tid & 63;
  const int hi = lane >> 5, l31 = lane & 31;
  // XCD swizzle: the 16 blocks of one bh all share blockIdx%8 -> same XCD L2
  const int bidx = blockIdx.x;           // grid = 1024
  const int xcd = bidx & 7, slot = bidx >> 3;
  const int bh = xcd + 8 * (slot >> 4);  // 0..63
  const int qt = (slot & 15) * 4 + w;    // 0..63 (32-row q tile)
  const char* kbase = (const char*)kt + ((size_t)bh << 18);  // 32 tiles * 8KB
  const char* vbase = (const char*)vt + ((size_t)bh << 18);
  const ushort_t* Qp = qb + (size_t)bh * (S_ * 64) + qt * 32 * 64;

  // Q B-frags: lane holds Q[q=l31][dk = c*16 + hi*8 + e]
  bf16v8 qf[4];
#pragma unroll
  for (int c = 0; c < 4; ++c)
    qf[c] = *(const bf16v8*)(Qp + l31 * 64 + c * 16 + hi * 8);

  // ones B-fragment for the MFMA row-sum (bf16 1.0 = 0x3F80)
  const bf16v8 onesf = __builtin_bit_cast(
      bf16v8, u16x8{0x3F80, 0x3F80, 0x3F80, 0x3F80, 0x3F80, 0x3F80, 0x3F80, 0x3F80});

  // loop-invariant swizzled LDS byte offsets (row = l31, colByte = c*32+hi*16)
  // 16-slot XOR: 32 lanes -> 16 slots = 2-way = free (m136)
  int addr4[4];
#pragma unroll
  for (int c = 0; c < 4; ++c)
    addr4[c] = (l31 * 128 + c * 32 + hi * 16) ^ ((l31 & 15) << 4);

  f32x16 oa[2] = {};            // O[q][dv], dv-blocks of 32
  f32x16 oas = {};              // row sums, SAME register layout as oa

  // prologue: stage tile 0 into buffer 0 (4 loads/wave)
  ASTAGE(0);

#pragma unroll 2
  for (int t = 0; t < 31; ++t) {
    BAR();            // all waves done reading buf[(t+1)&1] (during iter t-1)
    ASTAGE(t + 1);    // 4 loads into buf[(t+1)&1]
    VMW("4");         // own tile-t loads landed; t+1's stay in flight
    BAR();            // all waves' tile-t loads landed
    ACOMPUTE(t);
  }
  BAR();
  VMW("0");           // last tile: drain (nothing left to overlap)
  BAR();
  ACOMPUTE(31);

  // normalize directly: row sums live in oas at the same reg->q mapping as oa.
  // ob region = buf0 (0..16KB): last compute used buf1, all waves past BAR.
  ushort_t* ob = (ushort_t*)(smem + w * 4096);
#pragma unroll
  for (int rq = 0; rq < 4; ++rq)
#pragma unroll
    for (int j = 0; j < 4; ++j) {
      float rv = 1.0f / oas[4 * rq + j];
      int row = 8 * rq + 4 * hi + j;
#pragma unroll
      for (int nb = 0; nb < 2; ++nb)
        ob[row * 64 + nb * 32 + l31] = f2bf(oa[nb][4 * rq + j] * rv);
    }
  asm volatile("s_waitcnt lgkmcnt(0)" ::: "memory");
  const int row = lane >> 1, hf = lane & 1;
  const int b = bh >> 4, h = bh & 15;
  const int rowg = b * 2048 + qt * 32 + row;     // global (b,s) row
  const int sx = (rowg >> 1) & 3;                // out-proj pre-swizzle
  size_t rbase = (size_t)rowg * 1024;
#pragma unroll
  for (int i = 0; i < 4; ++i) {
    bf16v8 v = *(const bf16v8*)&ob[row * 64 + hf * 32 + i * 8];
    int c = h * 8 + hf * 4 + i;                  // 16B-chunk index in row
    *(bf16v8*)(aout + rbase + (size_t)((c ^ sx) * 8)) = v;
  }
}

// ---------------------------------------------------------------------------
extern "C" void kernel_launch(void* const* d_in, const int* in_sizes, int n_in,
                              void* d_out, int out_size, void* d_ws, size_t ws_size,
                              hipStream_t stream) {
  const float* x = (const float*)d_in[0];
  const float* Wq = (const float*)d_in[1];
  const float* Wk = (const float*)d_in[2];
  const float* Wv = (const float*)d_in[3];
  const float* Wo = (const float*)d_in[4];
  float* out = (float*)d_out;

  // workspace layout (bytes)
  char* ws = (char*)d_ws;
  constexpr size_t OFF_XB = 0;                       // 16 MB  x bf16 pre-swz
  constexpr size_t OFF_WQKV = 16777216;              // 6 MB   [3][H][dk][D] pre-swz
  constexpr size_t OFF_WO = 23068672;                // 2 MB   [N][K] pre-swz
  constexpr size_t OFF_Q = 25165824;                 // 16 MB  [BH][S][64] raw
  constexpr size_t OFF_K = 41943040;                 // 16 MB  K tiled+attn-swz
  constexpr size_t OFF_V = 58720256;                 // 16 MB  V tiled+attn-swz
  constexpr size_t OFF_AO = 75497472;                // 16 MB  [8192][1024] pre-swz
  constexpr size_t WS_NEEDED = 92274688;
  if (ws_size < WS_NEEDED) return;  // refuse to scribble OOB

  ushort_t* xb = (ushort_t*)(ws + OFF_XB);
  ushort_t* wqkv_t = (ushort_t*)(ws + OFF_WQKV);
  ushort_t* wo_t = (ushort_t*)(ws + OFF_WO);
  ushort_t* q_buf = (ushort_t*)(ws + OFF_Q);
  ushort_t* k_t = (ushort_t*)(ws + OFF_K);
  ushort_t* v_t = (ushort_t*)(ws + OFF_V);
  ushort_t* a_out = (ushort_t*)(ws + OFF_AO);

  cast_x_kernel<<<(M_ * D_ / 8) / 256, 256, 0, stream>>>(x, xb);
  prep_wqkv_kernel<<<192, 256, 0, stream>>>(Wq, Wk, Wv, wqkv_t);
  prep_wo_kernel<<<64, 256, 0, stream>>>(Wo, wo_t);

  gemm256_qkv<<<(M_ / 256) * (NQKV_ / 256), 512, 131072, stream>>>(
      xb, wqkv_t, q_buf, k_t, v_t);

  attn_kernel<<<1024, 256, 0, stream>>>(q_buf, k_t, v_t, a_out);

  gemm128_op<<<(M_ / 128) * (D_ / 128), 256, 65536, stream>>>(a_out, wo_t, out);
}

// Round 19
// 192.295 us; speedup vs baseline: 1.0558x; 1.0052x over previous
//
#include <hip/hip_runtime.h>
#include <hip/hip_bf16.h>
#include <cstdint>
#include <cstddef>

// ---------------------------------------------------------------------------
// MHA: x[4,2048,1024] -> out[4,2048,1024], fp32 I/O, bf16 MFMA internals.
// ---------------------------------------------------------------------------

typedef __attribute__((ext_vector_type(8))) __bf16 bf16v8;
typedef __attribute__((ext_vector_type(4))) float f32x4;
typedef __attribute__((ext_vector_type(16))) float f32x16;
typedef __attribute__((ext_vector_type(8))) unsigned short u16x8;
typedef __attribute__((ext_vector_type(4))) unsigned u32x4;
typedef unsigned short ushort_t;

#define AS3(p) ((__attribute__((address_space(3))) void*)(p))
#define AS1C(p) ((const __attribute__((address_space(1))) void*)(p))

__device__ __forceinline__ ushort_t f2bf(float f) {
  unsigned u = __builtin_bit_cast(unsigned, f);
  unsigned r = u + 0x7FFFu + ((u >> 16) & 1u);   // RNE
  return (ushort_t)(r >> 16);
}

__device__ __forceinline__ unsigned cvt_pk_bf16(float lo, float hi) {
  unsigned r;
  asm("v_cvt_pk_bf16_f32 %0, %1, %2" : "=v"(r) : "v"(lo), "v"(hi));
  return r;
}

// v_permlane32_swap_b32 vdst, vsrc : vdst.hi <-> vsrc.lo (lane i+32 <-> lane i)
__device__ __forceinline__ void plswap(unsigned& x, unsigned& y) {
  asm("v_permlane32_swap_b32 %0, %1" : "+v"(x), "+v"(y));
}

// raw v_exp_f32 (2^x). Scores are bounded (|log2-score| < ~40): no overflow;
// subnormal flush-to-zero is the correct limit for vanished softmax terms.
__device__ __forceinline__ float exp2_raw(float x) {
  float r;
  asm("v_exp_f32 %0, %1" : "=v"(r) : "v"(x));
  return r;
}

constexpr int B_ = 4, S_ = 2048, D_ = 1024, H_ = 16, DK_ = 64;
constexpr int M_ = B_ * S_;          // 8192 rows (b,s)
constexpr int NQKV_ = 3 * H_ * DK_;  // 3072
// fold 1/sqrt(dk) * log2(e) into W_Q so scores are in log2-space
constexpr float QSCALE = 0.125f * 1.44269504088896f;

// ---------------------------------------------------------------------------
// Merged prep kernel: grid 4352 blocks, per-block-uniform branch.
//   [0,4096):    x fp32 -> bf16, ONE 16B chunk (8 elems) per thread:
//                4096 blocks x 256 thr = 2^20 chunks = M_*D_*2B / 16 exactly.
//   [4096,4288): W_QKV -> wqkv_t [p][h][dk][D] bf16 pre-swz (LDS transpose)
//   [4288,4352): W_O -> wo_t [N][K] bf16 pre-swz (LDS transpose)
// All outputs bit-identical to the r16 three-kernel version.
__global__ __launch_bounds__(256) void prep_all_kernel(
    const float* __restrict__ x, const float* __restrict__ Wq,
    const float* __restrict__ Wk, const float* __restrict__ Wv,
    const float* __restrict__ Wo, ushort_t* __restrict__ xb,
    ushort_t* __restrict__ wqkv_t, ushort_t* __restrict__ wo_t) {
  __shared__ ushort_t lt[64 * 264];
  const int blk = blockIdx.x;
  const int t = threadIdx.x;

  if (blk < 4096) {
    // ---- cast_x: exactly one 16B chunk per thread (r16 body) ----
    size_t i = (size_t)blk * 256 + t;    // 16B-chunk index < 2^20
    const float4* px = (const float4*)(x + i * 8);
    float4 a = px[0], b = px[1];
    u16x8 v;
    v[0] = f2bf(a.x); v[1] = f2bf(a.y); v[2] = f2bf(a.z); v[3] = f2bf(a.w);
    v[4] = f2bf(b.x); v[5] = f2bf(b.y); v[6] = f2bf(b.z); v[7] = f2bf(b.w);
    size_t di = i ^ ((i >> 8) & 3);
    *(u16x8*)(xb + di * 8) = v;
    return;
  }

  if (blk < 4288) {
    // ---- prep_wqkv ----
    const int b2 = blk - 4096;           // 192 = p(3) x h(16) x dchunk(4)
    const int p = b2 >> 6;
    const int rem = b2 & 63;
    const int h = rem >> 2, d0 = (rem & 3) << 8;
    const float* W = (p == 0) ? Wq : ((p == 1) ? Wk : Wv);
    const float sc = (p == 0) ? QSCALE : 1.0f;
    const int rt = t >> 4, cq = (t & 15) << 2;
#pragma unroll
    for (int it = 0; it < 16; ++it) {
      int r = it * 16 + rt;              // d-offset 0..255
      float4 v = *(const float4*)(W + (h << 16) + (size_t)(d0 + r) * 64 + cq);
      lt[(cq + 0) * 264 + r] = f2bf(v.x * sc);
      lt[(cq + 1) * 264 + r] = f2bf(v.y * sc);
      lt[(cq + 2) * 264 + r] = f2bf(v.z * sc);
      lt[(cq + 3) * 264 + r] = f2bf(v.w * sc);
    }
    __syncthreads();
    const int c8 = t & 31;               // 16B chunk within the 256-d segment
#pragma unroll
    for (int it = 0; it < 8; ++it) {
      int dk = it * 8 + (t >> 5);
      u16x8 v = *(const u16x8*)&lt[dk * 264 + c8 * 8];
      int s = (dk >> 1) & 3;
      *(u16x8*)(wqkv_t + ((p << 20) | (h << 16) | (dk << 10)) + d0 + ((c8 ^ s) << 3)) = v;
    }
    return;
  }

  // ---- prep_wo ----
  const int b3 = blk - 4288;             // 64 = ntile(16) x ktile(4)
  const int n0 = (b3 >> 2) << 6;
  const int k0 = (b3 & 3) << 8;
  const int rt = t >> 4, nq = (t & 15) << 2;
#pragma unroll
  for (int it = 0; it < 16; ++it) {
    int kr = it * 16 + rt;               // k-offset 0..255
    float4 v = *(const float4*)(Wo + (size_t)(k0 + kr) * 1024 + n0 + nq);
    lt[(nq + 0) * 264 + kr] = f2bf(v.x);
    lt[(nq + 1) * 264 + kr] = f2bf(v.y);
    lt[(nq + 2) * 264 + kr] = f2bf(v.z);
    lt[(nq + 3) * 264 + kr] = f2bf(v.w);
  }
  __syncthreads();
  const int c8 = t & 31;
#pragma unroll
  for (int it = 0; it < 8; ++it) {
    int nr = it * 8 + (t >> 5);
    u16x8 v = *(const u16x8*)&lt[nr * 264 + c8 * 8];
    int n = n0 + nr;
    int s = (n >> 1) & 3;
    *(u16x8*)(wo_t + (size_t)n * 1024 + k0 + ((c8 ^ s) << 3)) = v;
  }
}

// ---------------------------------------------------------------------------
// 256x256 QKV GEMM (r13 config, the measured optimum): BK=32, 8 waves (2Mx4N),
// 4-deep LDS ring (4 x 32KB = 128KB), counted vmcnt (prefetch 3, steady
// VMW(8)), raw s_barrier per tile, T2 swizzle via pre-swizzled sources (#21).
// Epilogue: C staged in the dead ring LDS (V third transposed), 16B coalesced
// scatter; K/V attn-tiles use the 16-slot XOR ((row&15)<<4): 2-way = free.
#define VMW(N) asm volatile("s_waitcnt vmcnt(" N ")" ::: "memory")
#define BAR() asm volatile("s_barrier" ::: "memory")

#define STAGE3(T)                                                                   \
  {                                                                                 \
    const int pb = (((T) + 3) & 3) * 32768;                                         \
    __builtin_amdgcn_global_load_lds(AS1C(gA0), AS3(lds + pb + wid * 1024), 16, 0, 0); \
    __builtin_amdgcn_global_load_lds(AS1C(gA1), AS3(lds + pb + 8192 + wid * 1024), 16, 0, 0); \
    __builtin_amdgcn_global_load_lds(AS1C(gB0), AS3(lds + pb + 16384 + wid * 1024), 16, 0, 0); \
    __builtin_amdgcn_global_load_lds(AS1C(gB1), AS3(lds + pb + 24576 + wid * 1024), 16, 0, 0); \
    gA0 += 32; gA1 += 32; gB0 += 32; gB1 += 32;                                     \
  }

#define TILE_BODY(T, VMSTR, DO_STAGE)                                               \
  {                                                                                 \
    const int cb = ((T) & 3) * 32768;                                               \
    VMW(VMSTR);                                                                     \
    BAR();                                                                          \
    if (DO_STAGE) STAGE3(T);                                                        \
    bf16v8 af[8], bfr[4];                                                           \
    _Pragma("unroll")                                                               \
    for (int i = 0; i < 8; ++i)                                                     \
      af[i] = *(const bf16v8*)(lds + cb + awo + i * 1024);                          \
    _Pragma("unroll")                                                               \
    for (int j = 0; j < 4; ++j)                                                     \
      bfr[j] = *(const bf16v8*)(lds + cb + bwo + j * 1024);                         \
    __builtin_amdgcn_s_setprio(1);                                                  \
    _Pragma("unroll")                                                               \
    for (int i = 0; i < 8; ++i)                                                     \
      _Pragma("unroll")                                                             \
      for (int j = 0; j < 4; ++j)                                                   \
        acc[i][j] = __builtin_amdgcn_mfma_f32_16x16x32_bf16(af[i], bfr[j], acc[i][j], 0, 0, 0); \
    __builtin_amdgcn_s_setprio(0);                                                  \
  }

__global__ __launch_bounds__(512) void gemm256_qkv(
    const ushort_t* __restrict__ A, const ushort_t* __restrict__ Bt,
    ushort_t* __restrict__ qb, ushort_t* __restrict__ kb, ushort_t* __restrict__ vt) {
  extern __shared__ __align__(16) char lds[];  // 131072 B = 4 bufs x (A16K+B16K)
  const int tid = threadIdx.x;
  const int wid = tid >> 6, lane = tid & 63;
  const int g = lane >> 4, lq = lane & 15;
  const int wm = wid >> 2, wn = wid & 3;
  // XCD-aware bijective swizzle (384 % 8 == 0): 48 consecutive wgs per XCD
  const int bid = blockIdx.x;
  const int wg = (bid & 7) * 48 + (bid >> 3);
  const int mb = wg / 12, nb = wg % 12;
  const int m0 = mb * 256, n0 = nb * 256;

  // swizzled per-lane ds_read col offset: chunk' = g ^ ((row>>1)&3), row&15==lq
  const int co = (g ^ ((lq >> 1) & 3)) * 16;
  const int awo = wm * 8192 + lq * 64 + co;            // A frag base (+i*1024)
  const int bwo = 16384 + wn * 4096 + lq * 64 + co;    // B frag base (+j*1024)

  // stage source pointers (linear copy; sources are pre-swizzled)
  const ushort_t* gA0 = A + (size_t)(m0 + (tid >> 2)) * 1024 + (tid & 3) * 8;
  const ushort_t* gA1 = gA0 + (size_t)128 * 1024;
  const ushort_t* gB0 = Bt + (size_t)(n0 + (tid >> 2)) * 1024 + (tid & 3) * 8;
  const ushort_t* gB1 = gB0 + (size_t)128 * 1024;

  f32x4 acc[8][4] = {};

  // prologue: stage K-tiles 0,1,2 (12 loads/wave in flight)
  STAGE3(-3); STAGE3(-2); STAGE3(-1);

  for (int t = 0; t < 28; ++t) TILE_BODY(t, "8", true);
  TILE_BODY(28, "8", true);   // stages tile 31
  TILE_BODY(29, "8", false);
  TILE_BODY(30, "4", false);
  TILE_BODY(31, "0", false);

  // ---- epilogue: acc -> LDS (bf16 C-tile; V third transposed) ----
  asm volatile("s_waitcnt lgkmcnt(0)" ::: "memory");
  BAR();
  const int p = n0 >> 10;  // uniform per block (256 | 1024)
  if (p == 2) {
    // transposed: element (row s, col v) at byte (col*512 + row*2) ^ ((col&7)<<4)
#pragma unroll
    for (int i = 0; i < 8; ++i)
#pragma unroll
      for (int j = 0; j < 4; ++j) {
        int col = wn * 64 + j * 16 + lq;
        int swz = (col & 7) << 4;
#pragma unroll
        for (int r = 0; r < 4; ++r) {
          int row = wm * 128 + i * 16 + g * 4 + r;
          *(ushort_t*)(lds + ((col * 512 + row * 2) ^ swz)) = f2bf(acc[i][j][r]);
        }
      }
  } else {
    // row-major: element (row,col) at byte (row*512 + col*2) ^ ((row&7)<<4)
#pragma unroll
    for (int i = 0; i < 8; ++i)
#pragma unroll
      for (int j = 0; j < 4; ++j) {
        int col = wn * 64 + j * 16 + lq;
#pragma unroll
        for (int r = 0; r < 4; ++r) {
          int row = wm * 128 + i * 16 + g * 4 + r;
          *(ushort_t*)(lds + ((row * 512 + col * 2) ^ ((row & 7) << 4))) = f2bf(acc[i][j][r]);
        }
      }
  }
  asm volatile("s_waitcnt lgkmcnt(0)" ::: "memory");
  BAR();

  // ---- coalesced 16B stores: 16 chunks/thread ----
  if (p == 0) {
#pragma unroll
    for (int it = 0; it < 16; ++it) {
      int ci = it * 512 + tid;
      int row = ci >> 5, ch = ci & 31;
      u16x8 v = *(const u16x8*)(lds + ((row * 512 + ch * 16) ^ ((row & 7) << 4)));
      int gcol = n0 + ch * 8;
      int h = (gcol >> 6) & 15, dd0 = gcol & 63;
      int grow = m0 + row;
      int b = grow >> 11, s = grow & 2047;
      size_t bh = (size_t)(b * 16 + h);
      *(u16x8*)(qb + (bh * 2048 + s) * 64 + dd0) = v;
    }
  } else if (p == 1) {
#pragma unroll
    for (int it = 0; it < 16; ++it) {
      int ci = it * 512 + tid;
      int row = ci >> 5, ch = ci & 31;
      u16x8 v = *(const u16x8*)(lds + ((row * 512 + ch * 16) ^ ((row & 7) << 4)));
      int gcol = n0 + ch * 8;
      int h = (gcol >> 6) & 15, dd0 = gcol & 63;
      int grow = m0 + row;
      int b = grow >> 11, s = grow & 2047;
      size_t bh = (size_t)(b * 16 + h);
      int tt = s >> 6, sIn = s & 63;
      int byte = (sIn * 128 + dd0 * 2) ^ ((sIn & 15) << 4);   // 16-slot XOR
      *(u16x8*)((char*)kb + (((size_t)bh * 32 + tt) << 13) + byte) = v;
    }
  } else {
#pragma unroll
    for (int it = 0; it < 16; ++it) {
      int ci = it * 512 + tid;
      int crow = ci >> 5, ch = ci & 31;   // crow = v-col index; ch*8 = s-chunk
      u16x8 v = *(const u16x8*)(lds + ((crow * 512 + ch * 16) ^ ((crow & 7) << 4)));
      int gcol = n0 + crow;
      int h = (gcol >> 6) & 15, dd = gcol & 63;
      int grow = m0 + ch * 8;
      int b = grow >> 11, s = grow & 2047;
      size_t bh = (size_t)(b * 16 + h);
      int tt = s >> 6, sIn0 = s & 63;
      int byte = (dd * 128 + sIn0 * 2) ^ ((dd & 15) << 4);    // 16-slot XOR
      *(u16x8*)((char*)vt + (((size_t)bh * 32 + tt) << 13) + byte) = v;
    }
  }
}

// ---------------------------------------------------------------------------
// Out-projection GEMM: C[8192][1024] fp32 = a_out x wo_t^T.
// 128x128 tile, BK=32, 4 waves, 4-deep 16KB ring (64KB LDS -> 2 blocks/CU),
// counted vmcnt, T2 swizzle via pre-swizzled sources.  Grid 512, XCD-swz.
#define PSTAGE(T)                                                                   \
  {                                                                                 \
    const int pb = ((T) & 3) * 16384;                                               \
    __builtin_amdgcn_global_load_lds(AS1C(gA0), AS3(lds + pb + wid * 1024), 16, 0, 0); \
    __builtin_amdgcn_global_load_lds(AS1C(gA1), AS3(lds + pb + 4096 + wid * 1024), 16, 0, 0); \
    __builtin_amdgcn_global_load_lds(AS1C(gB0), AS3(lds + pb + 8192 + wid * 1024), 16, 0, 0); \
    __builtin_amdgcn_global_load_lds(AS1C(gB1), AS3(lds + pb + 12288 + wid * 1024), 16, 0, 0); \
    gA0 += 32; gA1 += 32; gB0 += 32; gB1 += 32;                                     \
  }

#define PBODY(T, VMSTR, DO_STAGE)                                                   \
  {                                                                                 \
    const int cb = ((T) & 3) * 16384;                                               \
    VMW(VMSTR);                                                                     \
    BAR();                                                                          \
    if (DO_STAGE) PSTAGE((T) + 3);                                                  \
    bf16v8 af[4], bfr[4];                                                           \
    _Pragma("unroll")                                                               \
    for (int i = 0; i < 4; ++i)                                                     \
      af[i] = *(const bf16v8*)(lds + cb + awo + i * 1024);                          \
    _Pragma("unroll")                                                               \
    for (int j = 0; j < 4; ++j)                                                     \
      bfr[j] = *(const bf16v8*)(lds + cb + bwo + j * 1024);                         \
    __builtin_amdgcn_s_setprio(1);                                                  \
    _Pragma("unroll")                                                               \
    for (int i = 0; i < 4; ++i)                                                     \
      _Pragma("unroll")                                                             \
      for (int j = 0; j < 4; ++j)                                                   \
        acc[i][j] = __builtin_amdgcn_mfma_f32_16x16x32_bf16(af[i], bfr[j], acc[i][j], 0, 0, 0); \
    __builtin_amdgcn_s_setprio(0);                                                  \
  }

__global__ __launch_bounds__(256) void gemm128_op(
    const ushort_t* __restrict__ A, const ushort_t* __restrict__ Bt,
    float* __restrict__ Cf) {
  extern __shared__ __align__(16) char lds[];  // 65536 = 4 bufs x (A8K + B8K)
  const int tid = threadIdx.x;
  const int wid = tid >> 6, lane = tid & 63;
  const int g = lane >> 4, lq = lane & 15;
  const int wm = wid >> 1, wn = wid & 1;
  // XCD-aware bijective swizzle (512 % 8 == 0): 64 consecutive wgs per XCD
  const int bid = blockIdx.x;
  const int wg = (bid & 7) * 64 + (bid >> 3);
  const int mb = wg >> 3, nb = wg & 7;
  const int m0 = mb * 128, n0 = nb * 128;

  // swizzled per-lane ds_read col offset: chunk' = g ^ ((row>>1)&3), row&15==lq
  const int co = (g ^ ((lq >> 1) & 3)) * 16;
  const int awo = wm * 4096 + lq * 64 + co;           // A frag base (+i*1024)
  const int bwo = 8192 + wn * 4096 + lq * 64 + co;    // B frag base (+j*1024)

  // stage source pointers (linear copy; sources are pre-swizzled)
  const ushort_t* gA0 = A + (size_t)(m0 + (tid >> 2)) * 1024 + (tid & 3) * 8;
  const ushort_t* gA1 = gA0 + (size_t)64 * 1024;
  const ushort_t* gB0 = Bt + (size_t)(n0 + (tid >> 2)) * 1024 + (tid & 3) * 8;
  const ushort_t* gB1 = gB0 + (size_t)64 * 1024;

  f32x4 acc[4][4] = {};

  // prologue: stage K-tiles 0,1,2 (12 loads/wave in flight)
  PSTAGE(0); PSTAGE(1); PSTAGE(2);

  for (int t = 0; t < 29; ++t) PBODY(t, "8", true);   // t=28 stages tile 31
  PBODY(29, "8", false);
  PBODY(30, "4", false);
  PBODY(31, "0", false);

  // epilogue: direct fp32 stores (16-lane 64B runs)
#pragma unroll
  for (int i = 0; i < 4; ++i)
#pragma unroll
    for (int j = 0; j < 4; ++j)
#pragma unroll
      for (int r = 0; r < 4; ++r) {
        int row = m0 + wm * 64 + i * 16 + g * 4 + r;
        int col = n0 + wn * 64 + j * 16 + lq;
        Cf[(size_t)row * 1024 + col] = acc[i][j][r];
      }
}

// ---------------------------------------------------------------------------
// Flash attention v10: 32x32 swapped-QK^T, in-register P, NO-MAX softmax
// with the row-sum computed BY THE MFMA PIPE (ones B-fragment): the sum
// lands in an f32x16 accumulator with the SAME register layout as O ->
// normalization is a per-register multiply (no VALU tree/shfl/LDS bcast).
// KVBLK=64, 2-buf 32KB static LDS, grid 1024, counted-vmcnt double-barrier.
// K/V tiles use the 16-slot XOR ((row&15)<<4): 2-way LDS alias = free.
__device__ __forceinline__ void softpack(const f32x16& s0, const f32x16& s1,
                                         bf16v8& pa0, bf16v8& pa1,
                                         bf16v8& pa2, bf16v8& pa3) {
  float e0[16], e1[16];
#pragma unroll
  for (int r = 0; r < 16; ++r) e0[r] = exp2_raw(s0[r]);
#pragma unroll
  for (int r = 0; r < 16; ++r) e1[r] = exp2_raw(s1[r]);
  unsigned a0 = cvt_pk_bf16(e0[0], e0[1]), b0 = cvt_pk_bf16(e0[4], e0[5]);
  unsigned a1 = cvt_pk_bf16(e0[2], e0[3]), b1 = cvt_pk_bf16(e0[6], e0[7]);
  unsigned a2 = cvt_pk_bf16(e0[8], e0[9]), b2 = cvt_pk_bf16(e0[12], e0[13]);
  unsigned a3 = cvt_pk_bf16(e0[10], e0[11]), b3 = cvt_pk_bf16(e0[14], e0[15]);
  unsigned a4 = cvt_pk_bf16(e1[0], e1[1]), b4 = cvt_pk_bf16(e1[4], e1[5]);
  unsigned a5 = cvt_pk_bf16(e1[2], e1[3]), b5 = cvt_pk_bf16(e1[6], e1[7]);
  unsigned a6 = cvt_pk_bf16(e1[8], e1[9]), b6 = cvt_pk_bf16(e1[12], e1[13]);
  unsigned a7 = cvt_pk_bf16(e1[10], e1[11]), b7 = cvt_pk_bf16(e1[14], e1[15]);
  plswap(a0, b0); plswap(a1, b1); plswap(a2, b2); plswap(a3, b3);
  plswap(a4, b4); plswap(a5, b5); plswap(a6, b6); plswap(a7, b7);
  pa0 = __builtin_bit_cast(bf16v8, u32x4{a0, a1, b0, b1});  // kv  0..15
  pa1 = __builtin_bit_cast(bf16v8, u32x4{a2, a3, b2, b3});  // kv 16..31
  pa2 = __builtin_bit_cast(bf16v8, u32x4{a4, a5, b4, b5});  // kv 32..47
  pa3 = __builtin_bit_cast(bf16v8, u32x4{a6, a7, b6, b7});  // kv 48..63
}

#define MFMA32(a, b, c) __builtin_amdgcn_mfma_f32_32x32x16_bf16(a, b, c, 0, 0, 0)

#define ASTAGE(T)                                                                   \
  {                                                                                 \
    const int pb = ((T) & 1) * 16384;                                               \
    const char* ks = kbase + ((size_t)(T) << 13);                                   \
    const char* vs = vbase + ((size_t)(T) << 13);                                   \
    _Pragma("unroll")                                                               \
    for (int j = 0; j < 2; ++j) {                                                   \
      __builtin_amdgcn_global_load_lds(AS1C(ks + w * 2048 + j * 1024 + lane * 16),  \
                                       AS3(smem + pb + w * 2048 + j * 1024), 16, 0, 0); \
      __builtin_amdgcn_global_load_lds(AS1C(vs + w * 2048 + j * 1024 + lane * 16),  \
                                       AS3(smem + pb + 8192 + w * 2048 + j * 1024), 16, 0, 0); \
    }                                                                               \
  }

#define ACOMPUTE(T)                                                                 \
  {                                                                                 \
    const char* bk = smem + ((T) & 1) * 16384;                                      \
    bf16v8 kf0[4], kf1[4], vfr[2][4];                                               \
    _Pragma("unroll")                                                               \
    for (int c = 0; c < 4; ++c) {                                                   \
      kf0[c] = *(const bf16v8*)(bk + addr4[c]);                                     \
      kf1[c] = *(const bf16v8*)(bk + addr4[c] + 4096);                              \
    }                                                                               \
    _Pragma("unroll")                                                               \
    for (int nb = 0; nb < 2; ++nb)                                                  \
      _Pragma("unroll")                                                             \
      for (int ks2 = 0; ks2 < 4; ++ks2)                                             \
        vfr[nb][ks2] = *(const bf16v8*)(bk + addr4[ks2] + 8192 + nb * 4096);        \
    f32x16 s0 = {}, s1 = {};                                                        \
    __builtin_amdgcn_s_setprio(1);                                                  \
    _Pragma("unroll")                                                               \
    for (int c = 0; c < 4; ++c) {                                                   \
      s0 = MFMA32(kf0[c], qf[c], s0);                                               \
      s1 = MFMA32(kf1[c], qf[c], s1);                                               \
    }                                                                               \
    __builtin_amdgcn_s_setprio(0);                                                  \
    bf16v8 pa0, pa1, pa2, pa3;                                                      \
    softpack(s0, s1, pa0, pa1, pa2, pa3);                                           \
    __builtin_amdgcn_s_setprio(1);                                                  \
    _Pragma("unroll")                                                               \
    for (int nb = 0; nb < 2; ++nb) {                                                \
      oa[nb] = MFMA32(pa0, vfr[nb][0], oa[nb]);                                     \
      oa[nb] = MFMA32(pa1, vfr[nb][1], oa[nb]);                                     \
      oa[nb] = MFMA32(pa2, vfr[nb][2], oa[nb]);                                     \
      oa[nb] = MFMA32(pa3, vfr[nb][3], oa[nb]);                                     \
    }                                                                               \
    oas = MFMA32(pa0, onesf, oas);                                                  \
    oas = MFMA32(pa1, onesf, oas);                                                  \
    oas = MFMA32(pa2, onesf, oas);                                                  \
    oas = MFMA32(pa3, onesf, oas);                                                  \
    __builtin_amdgcn_s_setprio(0);                                                  \
  }

__global__ __launch_bounds__(256) void attn_kernel(const ushort_t* __restrict__ qb,
                                                   const ushort_t* __restrict__ kt,
                                                   const ushort_t* __restrict__ vt,
                                                   ushort_t* __restrict__ aout) {
  __shared__ __align__(16) char smem[32768];
  const int tid = threadIdx.x;
  const int w = tid >> 6, lane = tid & 63;
  const int hi = lane >> 5, l31 = lane & 31;
  // XCD swizzle: the 16 blocks of one bh all share blockIdx%8 -> same XCD L2
  const int bidx = blockIdx.x;           // grid = 1024
  const int xcd = bidx & 7, slot = bidx >> 3;
  const int bh = xcd + 8 * (slot >> 4);  // 0..63
  const int qt = (slot & 15) * 4 + w;    // 0..63 (32-row q tile)
  const char* kbase = (const char*)kt + ((size_t)bh << 18);  // 32 tiles * 8KB
  const char* vbase = (const char*)vt + ((size_t)bh << 18);
  const ushort_t* Qp = qb + (size_t)bh * (S_ * 64) + qt * 32 * 64;

  // Q B-frags: lane holds Q[q=l31][dk = c*16 + hi*8 + e]
  bf16v8 qf[4];
#pragma unroll
  for (int c = 0; c < 4; ++c)
    qf[c] = *(const bf16v8*)(Qp + l31 * 64 + c * 16 + hi * 8);

  // ones B-fragment for the MFMA row-sum (bf16 1.0 = 0x3F80)
  const bf16v8 onesf = __builtin_bit_cast(
      bf16v8, u16x8{0x3F80, 0x3F80, 0x3F80, 0x3F80, 0x3F80, 0x3F80, 0x3F80, 0x3F80});

  // loop-invariant swizzled LDS byte offsets (row = l31, colByte = c*32+hi*16)
  // 16-slot XOR: 32 lanes -> 16 slots = 2-way = free (m136)
  int addr4[4];
#pragma unroll
  for (int c = 0; c < 4; ++c)
    addr4[c] = (l31 * 128 + c * 32 + hi * 16) ^ ((l31 & 15) << 4);

  f32x16 oa[2] = {};            // O[q][dv], dv-blocks of 32
  f32x16 oas = {};              // row sums, SAME register layout as oa

  // prologue: stage tile 0 into buffer 0 (4 loads/wave)
  ASTAGE(0);

#pragma unroll 2
  for (int t = 0; t < 31; ++t) {
    BAR();            // all waves done reading buf[(t+1)&1] (during iter t-1)
    ASTAGE(t + 1);    // 4 loads into buf[(t+1)&1]
    VMW("4");         // own tile-t loads landed; t+1's stay in flight
    BAR();            // all waves' tile-t loads landed
    ACOMPUTE(t);
  }
  BAR();
  VMW("0");           // last tile: drain (nothing left to overlap)
  BAR();
  ACOMPUTE(31);

  // normalize directly: row sums live in oas at the same reg->q mapping as oa.
  // ob region = buf0 (0..16KB): last compute used buf1, all waves past BAR.
  ushort_t* ob = (ushort_t*)(smem + w * 4096);
#pragma unroll
  for (int rq = 0; rq < 4; ++rq)
#pragma unroll
    for (int j = 0; j < 4; ++j) {
      float rv = 1.0f / oas[4 * rq + j];
      int row = 8 * rq + 4 * hi + j;
#pragma unroll
      for (int nb = 0; nb < 2; ++nb)
        ob[row * 64 + nb * 32 + l31] = f2bf(oa[nb][4 * rq + j] * rv);
    }
  asm volatile("s_waitcnt lgkmcnt(0)" ::: "memory");
  const int row = lane >> 1, hf = lane & 1;
  const int b = bh >> 4, h = bh & 15;
  const int rowg = b * 2048 + qt * 32 + row;     // global (b,s) row
  const int sx = (rowg >> 1) & 3;                // out-proj pre-swizzle
  size_t rbase = (size_t)rowg * 1024;
#pragma unroll
  for (int i = 0; i < 4; ++i) {
    bf16v8 v = *(const bf16v8*)&ob[row * 64 + hf * 32 + i * 8];
    int c = h * 8 + hf * 4 + i;                  // 16B-chunk index in row
    *(bf16v8*)(aout + rbase + (size_t)((c ^ sx) * 8)) = v;
  }
}

// ---------------------------------------------------------------------------
extern "C" void kernel_launch(void* const* d_in, const int* in_sizes, int n_in,
                              void* d_out, int out_size, void* d_ws, size_t ws_size,
                              hipStream_t stream) {
  const float* x = (const float*)d_in[0];
  const float* Wq = (const float*)d_in[1];
  const float* Wk = (const float*)d_in[2];
  const float* Wv = (const float*)d_in[3];
  const float* Wo = (const float*)d_in[4];
  float* out = (float*)d_out;

  // workspace layout (bytes)
  char* ws = (char*)d_ws;
  constexpr size_t OFF_XB = 0;                       // 16 MB  x bf16 pre-swz
  constexpr size_t OFF_WQKV = 16777216;              // 6 MB   [3][H][dk][D] pre-swz
  constexpr size_t OFF_WO = 23068672;                // 2 MB   [N][K] pre-swz
  constexpr size_t OFF_Q = 25165824;                 // 16 MB  [BH][S][64] raw
  constexpr size_t OFF_K = 41943040;                 // 16 MB  K tiled+attn-swz
  constexpr size_t OFF_V = 58720256;                 // 16 MB  V tiled+attn-swz
  constexpr size_t OFF_AO = 75497472;                // 16 MB  [8192][1024] pre-swz
  constexpr size_t WS_NEEDED = 92274688;
  if (ws_size < WS_NEEDED) return;  // refuse to scribble OOB

  ushort_t* xb = (ushort_t*)(ws + OFF_XB);
  ushort_t* wqkv_t = (ushort_t*)(ws + OFF_WQKV);
  ushort_t* wo_t = (ushort_t*)(ws + OFF_WO);
  ushort_t* q_buf = (ushort_t*)(ws + OFF_Q);
  ushort_t* k_t = (ushort_t*)(ws + OFF_K);
  ushort_t* v_t = (ushort_t*)(ws + OFF_V);
  ushort_t* a_out = (ushort_t*)(ws + OFF_AO);

  prep_all_kernel<<<4352, 256, 0, stream>>>(x, Wq, Wk, Wv, Wo, xb, wqkv_t, wo_t);

  gemm256_qkv<<<(M_ / 256) * (NQKV_ / 256), 512, 131072, stream>>>(
      xb, wqkv_t, q_buf, k_t, v_t);

  attn_kernel<<<1024, 256, 0, stream>>>(q_buf, k_t, v_t, a_out);

  gemm128_op<<<(M_ / 128) * (D_ / 128), 256, 65536, stream>>>(a_out, wo_t, out);
}